// Round 2
// baseline (4827.351 us; speedup 1.0000x reference)
//
#include <hip/hip_runtime.h>
#include <math.h>

#define S_ 2048
#define T_ 64
#define F_ 16
#define D_ 256
#define NS_ 4
#define E_ 128
#define H_ 8
#define KC_ 32
#define SD_ (S_*D_)

// ---------------- helpers ----------------
__device__ __forceinline__ float warp_sum64(float v){
  #pragma unroll
  for (int o=32;o>=1;o>>=1) v += __shfl_xor(v,o);
  return v;
}
__device__ __forceinline__ float warp_max64(float v){
  #pragma unroll
  for (int o=32;o>=1;o>>=1) v = fmaxf(v,__shfl_xor(v,o));
  return v;
}
__device__ __forceinline__ float softplus_f(float v){
  return fmaxf(v,0.f) + log1pf(__expf(-fabsf(v)));
}
__device__ __forceinline__ float tanh_f(float v){
  float t = __expf(-2.f*fabsf(v));
  float r = (1.f-t)/(1.f+t);
  return copysignf(r, v);
}

// ---------------- positional encoding ----------------
__global__ void pe_kernel(float* __restrict__ pe){
  int i = blockIdx.x*256 + threadIdx.x;       // grid 64 -> 16384
  int t = i >> 8, d = i & 255;
  int ii = d >> 1;
  float w = __expf(-(float)ii * (logf(10000.f)/128.f));
  float ang = (float)t * w;
  pe[i] = (d & 1) ? cosf(ang) : sinf(ang);
}

// ---------------- stage A: per-stock temporal pipeline ----------------
// LDS: 64KB hbuf + 64KB aux + 512B = 131.5KB (<160KB gfx950 WG limit) -> 1 block/CU
__launch_bounds__(256,1)
__global__ void stageA_kernel(
    const float* __restrict__ x, const float* __restrict__ pe,
    const float* __restrict__ Wemb, const float* __restrict__ bemb,
    const float* __restrict__ Wq, const float* __restrict__ bq,
    const float* __restrict__ Wk, const float* __restrict__ bk,
    const float* __restrict__ Wv, const float* __restrict__ bv,
    const float* __restrict__ Wo, const float* __restrict__ bo,
    const float* __restrict__ ln1g, const float* __restrict__ ln1b,
    const float* __restrict__ Wint, const float* __restrict__ bint,
    const float* __restrict__ Wmix, const float* __restrict__ bmix,
    const float* __restrict__ ln2g, const float* __restrict__ ln2b,
    const float* __restrict__ Wt, const float* __restrict__ bt,
    const float* __restrict__ vt, float* __restrict__ xs)
{
  __shared__ float hbuf[T_][D_];     // 64KB
  __shared__ float aux[16384];       // 64KB multipurpose
  __shared__ float smallb[2*T_];

  const int j  = threadIdx.x;
  const int s  = blockIdx.x;
  const int rg = j >> 6;     // wave id / row-group of 16
  const int c0 = j & 63;     // lane

  // ---- stage x[s] into aux ----
  {
    const float* xp = x + (long)s*T_*F_;
    for (int i=j; i<T_*F_; i+=256) aux[i] = xp[i];
  }
  __syncthreads();

  // ---- embedding + PE ----
  {
    float acc[16][4];
    #pragma unroll
    for (int r=0;r<16;++r){acc[r][0]=0;acc[r][1]=0;acc[r][2]=0;acc[r][3]=0;}
    #pragma unroll
    for (int k=0;k<F_;++k){
      float w0=Wemb[k*D_+c0], w1=Wemb[k*D_+c0+64], w2=Wemb[k*D_+c0+128], w3=Wemb[k*D_+c0+192];
      #pragma unroll
      for (int r=0;r<16;++r){
        float hv = aux[(rg*16+r)*F_+k];
        acc[r][0]+=hv*w0; acc[r][1]+=hv*w1; acc[r][2]+=hv*w2; acc[r][3]+=hv*w3;
      }
    }
    float b0=bemb[c0],b1=bemb[c0+64],b2=bemb[c0+128],b3=bemb[c0+192];
    __syncthreads();  // x-stage reads done before later aux writes
    #pragma unroll
    for (int r=0;r<16;++r){
      int t = rg*16+r;
      hbuf[t][c0]     = acc[r][0]+b0+pe[t*D_+c0];
      hbuf[t][c0+64]  = acc[r][1]+b1+pe[t*D_+c0+64];
      hbuf[t][c0+128] = acc[r][2]+b2+pe[t*D_+c0+128];
      hbuf[t][c0+192] = acc[r][3]+b3+pe[t*D_+c0+192];
    }
  }
  __syncthreads();

  // ---- attention ----
  float* qbuf = aux;                     // [64][36]
  float* kTb  = aux + 64*36;             // [32][68]
  float* vbuf = aux + 64*36 + 32*68;     // [64][36]
  float* scb  = aux + 64*36*2 + 32*68;   // [64][68]

  float oacc[T_];
  {
    float bov = bo[j];
    #pragma unroll
    for (int t=0;t<T_;++t) oacc[t]=bov;
  }
  const float rs = 0.17677669529663687f;  // 1/sqrt(32)

  for (int hh=0; hh<H_; ++hh){
    // q,k,v for this head
    {
      const int cp = j & 31, tg = j >> 5;
      const int col = hh*32+cp;
      float qa[8]={0,0,0,0,0,0,0,0}, ka[8]={0,0,0,0,0,0,0,0}, va[8]={0,0,0,0,0,0,0,0};
      for (int k=0;k<D_;k+=4){
        float wq0=Wq[(k+0)*D_+col],wq1=Wq[(k+1)*D_+col],wq2=Wq[(k+2)*D_+col],wq3=Wq[(k+3)*D_+col];
        float wk0=Wk[(k+0)*D_+col],wk1=Wk[(k+1)*D_+col],wk2=Wk[(k+2)*D_+col],wk3=Wk[(k+3)*D_+col];
        float wv0=Wv[(k+0)*D_+col],wv1=Wv[(k+1)*D_+col],wv2=Wv[(k+2)*D_+col],wv3=Wv[(k+3)*D_+col];
        #pragma unroll
        for (int r=0;r<8;++r){
          float4 hv = *(const float4*)&hbuf[tg*8+r][k];
          qa[r] += hv.x*wq0+hv.y*wq1+hv.z*wq2+hv.w*wq3;
          ka[r] += hv.x*wk0+hv.y*wk1+hv.z*wk2+hv.w*wk3;
          va[r] += hv.x*wv0+hv.y*wv1+hv.z*wv2+hv.w*wv3;
        }
      }
      float bqv=bq[col],bkv=bk[col],bvv=bv[col];
      #pragma unroll
      for (int r=0;r<8;++r){
        int t = tg*8+r;
        qbuf[t*36+cp]=(qa[r]+bqv)*rs;
        kTb[cp*68+t]=ka[r]+bkv;
        vbuf[t*36+cp]=va[r]+bvv;
      }
    }
    __syncthreads();
    // scores + softmax: thread: tk=c0, rows rg*16..+16
    {
      float sa[16];
      #pragma unroll
      for (int r=0;r<16;++r) sa[r]=0.f;
      for (int d=0; d<32; ++d){
        float kv = kTb[d*68+c0];
        #pragma unroll
        for (int r=0;r<16;++r) sa[r] += qbuf[(rg*16+r)*36+d]*kv;
      }
      #pragma unroll
      for (int r=0;r<16;++r){
        float m  = warp_max64(sa[r]);
        float e  = __expf(sa[r]-m);
        float ss = warp_sum64(e);
        scb[(rg*16+r)*68+c0] = e/ss;
      }
    }
    __syncthreads();
    // o_h = att @ v  -> overwrite qbuf
    {
      const int d = j & 31, tg = j >> 5;
      float oa[8]={0,0,0,0,0,0,0,0};
      for (int tk=0; tk<T_; tk+=4){
        float v0=vbuf[(tk+0)*36+d], v1=vbuf[(tk+1)*36+d], v2=vbuf[(tk+2)*36+d], v3=vbuf[(tk+3)*36+d];
        #pragma unroll
        for (int r=0;r<8;++r){
          float4 av = *(const float4*)&scb[(tg*8+r)*68+tk];
          oa[r] += av.x*v0+av.y*v1+av.z*v2+av.w*v3;
        }
      }
      #pragma unroll
      for (int r=0;r<8;++r) qbuf[(tg*8+r)*36+d] = oa[r];
    }
    __syncthreads();
    // accumulate o_h @ Wo-block into oacc (column = j)
    {
      for (int kk=0; kk<32; kk+=4){
        float w0=Wo[(hh*32+kk+0)*D_+j];
        float w1=Wo[(hh*32+kk+1)*D_+j];
        float w2=Wo[(hh*32+kk+2)*D_+j];
        float w3=Wo[(hh*32+kk+3)*D_+j];
        #pragma unroll
        for (int t=0;t<T_;++t){
          float4 ov = *(const float4*)&qbuf[t*36+kk];
          oacc[t] += ov.x*w0+ov.y*w1+ov.z*w2+ov.w*w3;
        }
      }
    }
    __syncthreads();
  }

  // ---- residual + LN1 ----
  {
    #pragma unroll
    for (int t=0;t<T_;++t) hbuf[t][j] += oacc[t];
  }
  __syncthreads();
  {
    float g0=ln1g[c0],g1=ln1g[c0+64],g2=ln1g[c0+128],g3=ln1g[c0+192];
    float bb0=ln1b[c0],bb1=ln1b[c0+64],bb2=ln1b[c0+128],bb3=ln1b[c0+192];
    for (int rr=0;rr<16;++rr){
      int t=rg*16+rr;
      float v0=hbuf[t][c0],v1=hbuf[t][c0+64],v2=hbuf[t][c0+128],v3=hbuf[t][c0+192];
      float sm=warp_sum64(v0+v1+v2+v3);
      float sq=warp_sum64(v0*v0+v1*v1+v2*v2+v3*v3);
      float mean=sm*(1.f/256.f);
      float inv=rsqrtf(fmaxf(sq*(1.f/256.f)-mean*mean,0.f)+1e-5f);
      hbuf[t][c0]    =(v0-mean)*inv*g0+bb0;
      hbuf[t][c0+64] =(v1-mean)*inv*g1+bb1;
      hbuf[t][c0+128]=(v2-mean)*inv*g2+bb2;
      hbuf[t][c0+192]=(v3-mean)*inv*g3+bb3;
    }
  }
  __syncthreads();

  // ---- intensity = softplus(h @ Wint + bint) -> aux ----
  {
    float acc[16][4];
    #pragma unroll
    for (int r=0;r<16;++r){acc[r][0]=0;acc[r][1]=0;acc[r][2]=0;acc[r][3]=0;}
    for (int k=0;k<D_;k+=4){
      float w[4][4];
      #pragma unroll
      for (int i=0;i<4;++i){
        w[i][0]=Wint[(k+i)*D_+c0];     w[i][1]=Wint[(k+i)*D_+c0+64];
        w[i][2]=Wint[(k+i)*D_+c0+128]; w[i][3]=Wint[(k+i)*D_+c0+192];
      }
      #pragma unroll
      for (int r=0;r<16;++r){
        float4 hv = *(const float4*)&hbuf[rg*16+r][k];
        #pragma unroll
        for (int m=0;m<4;++m)
          acc[r][m] += hv.x*w[0][m]+hv.y*w[1][m]+hv.z*w[2][m]+hv.w*w[3][m];
      }
    }
    float b0=bint[c0],b1=bint[c0+64],b2=bint[c0+128],b3=bint[c0+192];
    #pragma unroll
    for (int r=0;r<16;++r){
      int t=rg*16+r;
      aux[t*256+c0]     = softplus_f(acc[r][0]+b0);
      aux[t*256+c0+64]  = softplus_f(acc[r][1]+b1);
      aux[t*256+c0+128] = softplus_f(acc[r][2]+b2);
      aux[t*256+c0+192] = softplus_f(acc[r][3]+b3);
    }
  }
  __syncthreads();

  // ---- z = relu([h|intensity] @ Wmix + bmix) ; LN2 ----
  {
    float acc[16][4];
    #pragma unroll
    for (int r=0;r<16;++r){acc[r][0]=0;acc[r][1]=0;acc[r][2]=0;acc[r][3]=0;}
    for (int k=0;k<D_;k+=4){
      float w[4][4];
      #pragma unroll
      for (int i=0;i<4;++i){
        w[i][0]=Wmix[(k+i)*D_+c0];     w[i][1]=Wmix[(k+i)*D_+c0+64];
        w[i][2]=Wmix[(k+i)*D_+c0+128]; w[i][3]=Wmix[(k+i)*D_+c0+192];
      }
      #pragma unroll
      for (int r=0;r<16;++r){
        float4 hv = *(const float4*)&hbuf[rg*16+r][k];
        #pragma unroll
        for (int m=0;m<4;++m)
          acc[r][m] += hv.x*w[0][m]+hv.y*w[1][m]+hv.z*w[2][m]+hv.w*w[3][m];
      }
    }
    for (int k=0;k<D_;k+=4){
      float w[4][4];
      #pragma unroll
      for (int i=0;i<4;++i){
        w[i][0]=Wmix[(256+k+i)*D_+c0];     w[i][1]=Wmix[(256+k+i)*D_+c0+64];
        w[i][2]=Wmix[(256+k+i)*D_+c0+128]; w[i][3]=Wmix[(256+k+i)*D_+c0+192];
      }
      #pragma unroll
      for (int r=0;r<16;++r){
        float4 hv = *(const float4*)&aux[(rg*16+r)*256+k];
        #pragma unroll
        for (int m=0;m<4;++m)
          acc[r][m] += hv.x*w[0][m]+hv.y*w[1][m]+hv.z*w[2][m]+hv.w*w[3][m];
      }
    }
    float b0=bmix[c0],b1=bmix[c0+64],b2=bmix[c0+128],b3=bmix[c0+192];
    __syncthreads();   // everyone done reading hbuf
    #pragma unroll
    for (int r=0;r<16;++r){
      int t=rg*16+r;
      hbuf[t][c0]     = fmaxf(acc[r][0]+b0,0.f);
      hbuf[t][c0+64]  = fmaxf(acc[r][1]+b1,0.f);
      hbuf[t][c0+128] = fmaxf(acc[r][2]+b2,0.f);
      hbuf[t][c0+192] = fmaxf(acc[r][3]+b3,0.f);
    }
  }
  __syncthreads();
  {
    float g0=ln2g[c0],g1=ln2g[c0+64],g2=ln2g[c0+128],g3=ln2g[c0+192];
    float bb0=ln2b[c0],bb1=ln2b[c0+64],bb2=ln2b[c0+128],bb3=ln2b[c0+192];
    for (int rr=0;rr<16;++rr){
      int t=rg*16+rr;
      float v0=hbuf[t][c0],v1=hbuf[t][c0+64],v2=hbuf[t][c0+128],v3=hbuf[t][c0+192];
      float sm=warp_sum64(v0+v1+v2+v3);
      float sq=warp_sum64(v0*v0+v1*v1+v2*v2+v3*v3);
      float mean=sm*(1.f/256.f);
      float inv=rsqrtf(fmaxf(sq*(1.f/256.f)-mean*mean,0.f)+1e-5f);
      hbuf[t][c0]    =(v0-mean)*inv*g0+bb0;
      hbuf[t][c0+64] =(v1-mean)*inv*g1+bb1;
      hbuf[t][c0+128]=(v2-mean)*inv*g2+bb2;
      hbuf[t][c0+192]=(v3-mean)*inv*g3+bb3;
    }
  }
  __syncthreads();

  // ---- u = tanh(h@Wt + bt) -> aux ----
  {
    float acc[16][4];
    #pragma unroll
    for (int r=0;r<16;++r){acc[r][0]=0;acc[r][1]=0;acc[r][2]=0;acc[r][3]=0;}
    for (int k=0;k<D_;k+=4){
      float w[4][4];
      #pragma unroll
      for (int i=0;i<4;++i){
        w[i][0]=Wt[(k+i)*D_+c0];     w[i][1]=Wt[(k+i)*D_+c0+64];
        w[i][2]=Wt[(k+i)*D_+c0+128]; w[i][3]=Wt[(k+i)*D_+c0+192];
      }
      #pragma unroll
      for (int r=0;r<16;++r){
        float4 hv = *(const float4*)&hbuf[rg*16+r][k];
        #pragma unroll
        for (int m=0;m<4;++m)
          acc[r][m] += hv.x*w[0][m]+hv.y*w[1][m]+hv.z*w[2][m]+hv.w*w[3][m];
      }
    }
    float b0=bt[c0],b1=bt[c0+64],b2=bt[c0+128],b3=bt[c0+192];
    #pragma unroll
    for (int r=0;r<16;++r){
      int t=rg*16+r;
      aux[t*256+c0]     = tanh_f(acc[r][0]+b0);
      aux[t*256+c0+64]  = tanh_f(acc[r][1]+b1);
      aux[t*256+c0+128] = tanh_f(acc[r][2]+b2);
      aux[t*256+c0+192] = tanh_f(acc[r][3]+b3);
    }
  }
  __syncthreads();

  // ---- temporal attention pooling ----
  {
    float vt0=vt[c0],vt1=vt[c0+64],vt2=vt[c0+128],vt3=vt[c0+192];
    for (int rr=0;rr<16;++rr){
      int t=rg*16+rr;
      float p = aux[t*256+c0]*vt0+aux[t*256+c0+64]*vt1+aux[t*256+c0+128]*vt2+aux[t*256+c0+192]*vt3;
      p = warp_sum64(p);
      if (c0==0) smallb[t]=p;
    }
  }
  __syncthreads();
  if (j < 64){
    float v = smallb[j];
    float m = warp_max64(v);
    float e = __expf(v-m);
    float ssum = warp_sum64(e);
    smallb[64+j] = e/ssum;
  }
  __syncthreads();
  {
    float acc=0.f;
    #pragma unroll 8
    for (int t=0;t<T_;++t) acc += smallb[64+t]*hbuf[t][j];
    xs[(long)s*D_+j] = acc;
  }
}

// ---------------- hypergraph prep ----------------
__global__ void hg_deg(const float* __restrict__ Hinc, float* __restrict__ Dv, float* __restrict__ De){
  const int n = blockIdx.y, s0 = blockIdx.x*64;   // grid (32, NS)
  const float* Hp = Hinc + (long)n*S_*E_;
  const int j = threadIdx.x;
  {
    int r = j>>2, q = j&3;
    const float* rp = Hp + (long)(s0+r)*E_ + q*32;
    float sm=0;
    #pragma unroll
    for (int e=0;e<32;++e) sm += rp[e];
    sm += __shfl_xor(sm,1); sm += __shfl_xor(sm,2);
    if (q==0) Dv[n*S_+s0+r]=sm+1e-6f;
  }
  if (j < E_){
    float cs=0;
    for (int ss=0;ss<64;++ss) cs += Hp[(long)(s0+ss)*E_+j];
    atomicAdd(&De[n*E_+j], cs);   // integer-valued fp32 adds: exact, deterministic
  }
}

__global__ void hg_scale(const float* __restrict__ Hinc, const float* __restrict__ Dv,
                         const float* __restrict__ De, float* __restrict__ Hn, float* __restrict__ HnD){
  long i = (long)blockIdx.x*256+threadIdx.x;   // grid 4096
  int n = (int)(i >> 18);
  int rem = (int)(i & 262143);
  int srow = rem >> 7;
  int e = rem & 127;
  float h = Hinc[i];
  float hn = h * rsqrtf(Dv[n*S_+srow]);
  Hn[i] = hn;
  HnD[i] = hn / (De[n*E_+e]+1e-6f);
}

// P-partial: Ppart[n][kc] = Hn_chunk^T @ M_chunk  (chunk = 64 rows of S)
__launch_bounds__(256,1)
__global__ void hg_phase1(const float* __restrict__ Hn, const float* __restrict__ M,
                          long mz, float* __restrict__ Ppart)
{
  __shared__ float hl[64*E_];
  __shared__ float ml[64*D_];
  const int kc = blockIdx.x, n = blockIdx.y;
  const int j = threadIdx.x;
  const float* Hp = Hn + ((long)n*S_ + (long)kc*64)*E_;
  const float* Mp = M + (long)n*mz + (long)kc*64*D_;
  for (int i=j*4; i<64*E_; i+=1024) *(float4*)&hl[i] = *(const float4*)&Hp[i];
  for (int i=j*4; i<64*D_; i+=1024) *(float4*)&ml[i] = *(const float4*)&Mp[i];
  __syncthreads();
  const int eg = j & 15, dg = j >> 4;
  float acc[8][16];
  #pragma unroll
  for (int e=0;e<8;++e){
    #pragma unroll
    for (int d=0;d<16;++d) acc[e][d]=0.f;
  }
  for (int ss=0; ss<64; ++ss){
    float hv[8], mv[16];
    *(float4*)&hv[0] = *(const float4*)&hl[ss*E_+eg*8];
    *(float4*)&hv[4] = *(const float4*)&hl[ss*E_+eg*8+4];
    *(float4*)&mv[0]  = *(const float4*)&ml[ss*D_+dg*16];
    *(float4*)&mv[4]  = *(const float4*)&ml[ss*D_+dg*16+4];
    *(float4*)&mv[8]  = *(const float4*)&ml[ss*D_+dg*16+8];
    *(float4*)&mv[12] = *(const float4*)&ml[ss*D_+dg*16+12];
    #pragma unroll
    for (int e=0;e<8;++e){
      #pragma unroll
      for (int d=0;d<16;++d) acc[e][d] += hv[e]*mv[d];
    }
  }
  float* Pp = Ppart + (long)(n*KC_+kc)*E_*D_;
  #pragma unroll
  for (int e=0;e<8;++e){
    int erow = eg*8+e;
    #pragma unroll
    for (int d4=0;d4<16;d4+=4){
      float4 v = make_float4(acc[e][d4],acc[e][d4+1],acc[e][d4+2],acc[e][d4+3]);
      *(float4*)&Pp[(long)erow*D_ + dg*16 + d4] = v;
    }
  }
}

__global__ void hg_reduceP(const float* __restrict__ Ppart, float* __restrict__ P){
  const int n = blockIdx.y;
  int base = blockIdx.x*4096;    // grid (8, NS)
  for (int i = base + threadIdx.x; i < base+4096; i += 256){
    const float* pp = Ppart + (long)n*KC_*E_*D_ + i;
    float a = 0;
    #pragma unroll
    for (int kc=0;kc<KC_;++kc) a += pp[(long)kc*E_*D_];
    P[(long)n*E_*D_ + i] = a;
  }
}

// out = filt * (c1*X1 + c2*X2 + c3*(HnD @ P))
// NOTE: in-place safe when out aliases X1 or X2: each element is read and
// written by exactly one thread, read-before-write.
__launch_bounds__(256,1)
__global__ void hg_phase2(const float* __restrict__ HnD, const float* __restrict__ P,
                          const float* __restrict__ X1, long x1z, float c1,
                          const float* __restrict__ X2, long x2z, float c2,
                          float c3, const float* __restrict__ filt, int usefilt,
                          float* __restrict__ out)
{
  __shared__ float al[E_*68];
  __shared__ float pl[E_*68];
  const int st = blockIdx.x*64, dt = blockIdx.y*64, n = blockIdx.z;
  const int j = threadIdx.x;
  {
    const int r = j >> 2, k0 = (j&3)*32;
    const float* hp = HnD + ((long)n*S_ + st + r)*E_ + k0;
    #pragma unroll
    for (int kk=0; kk<32; kk+=4){
      float4 v = *(const float4*)&hp[kk];
      al[(k0+kk+0)*68+r]=v.x;
      al[(k0+kk+1)*68+r]=v.y;
      al[(k0+kk+2)*68+r]=v.z;
      al[(k0+kk+3)*68+r]=v.w;
    }
  }
  for (int idx=j; idx<E_*16; idx+=256){
    int k = idx>>4, dsub = (idx&15)*4;
    *(float4*)&pl[k*68+dsub] = *(const float4*)&P[((long)n*E_+k)*D_ + dt + dsub];
  }
  __syncthreads();
  const int tx = j&15, ty = j>>4;
  float acc[4][4];
  #pragma unroll
  for (int i=0;i<4;++i){acc[i][0]=0;acc[i][1]=0;acc[i][2]=0;acc[i][3]=0;}
  for (int k=0;k<E_;++k){
    float4 a = *(const float4*)&al[k*68+ty*4];
    float4 b = *(const float4*)&pl[k*68+tx*4];
    acc[0][0]+=a.x*b.x; acc[0][1]+=a.x*b.y; acc[0][2]+=a.x*b.z; acc[0][3]+=a.x*b.w;
    acc[1][0]+=a.y*b.x; acc[1][1]+=a.y*b.y; acc[1][2]+=a.y*b.z; acc[1][3]+=a.y*b.w;
    acc[2][0]+=a.z*b.x; acc[2][1]+=a.z*b.y; acc[2][2]+=a.z*b.z; acc[2][3]+=a.z*b.w;
    acc[3][0]+=a.w*b.x; acc[3][1]+=a.w*b.y; acc[3][2]+=a.w*b.z; acc[3][3]+=a.w*b.w;
  }
  #pragma unroll
  for (int i=0;i<4;++i){
    int srow = st + ty*4 + i;
    float f = usefilt ? filt[srow] : 1.f;
    #pragma unroll
    for (int m=0;m<4;++m){
      int d = dt + tx*4+m;
      long li = (long)srow*D_ + d;
      float v = c3*acc[i][m];
      if (X1) v += c1*X1[x1z*n + li];
      if (X2) v += c2*X2[x2z*n + li];
      out[((long)n*S_ + srow)*D_ + d] = f*v;
    }
  }
}

// ---------------- generic fp32 GEMM (NN), 64x64 tile ----------------
__launch_bounds__(256,1)
__global__ void gemm_nn(const float* __restrict__ A, long az,
                        const float* __restrict__ B, long bz,
                        float* __restrict__ C, long cz,
                        int K, int N,
                        const float* __restrict__ bias, int act)
{
  __shared__ float al[32*68];
  __shared__ float bl[32*68];
  const int mt = blockIdx.x*64, nt = blockIdx.y*64, zz = blockIdx.z;
  const int j = threadIdx.x;
  const float* Ap = A + (long)az*zz;
  const float* Bp = B + (long)bz*zz;
  const int tx = j&15, ty = j>>4;
  float acc[4][4];
  #pragma unroll
  for (int i=0;i<4;++i){acc[i][0]=0;acc[i][1]=0;acc[i][2]=0;acc[i][3]=0;}
  for (int k0=0;k0<K;k0+=32){
    #pragma unroll
    for (int half=0; half<2; ++half){
      int idx = j + half*256;
      int r = idx>>3, kk=(idx&7)*4;
      float4 v = *(const float4*)&Ap[(long)(mt+r)*K + k0+kk];
      al[(kk+0)*68+r]=v.x; al[(kk+1)*68+r]=v.y; al[(kk+2)*68+r]=v.z; al[(kk+3)*68+r]=v.w;
    }
    #pragma unroll
    for (int half=0; half<2; ++half){
      int idx = j + half*256;
      int r = idx>>4, cc=(idx&15)*4;
      *(float4*)&bl[r*68+cc] = *(const float4*)&Bp[(long)(k0+r)*N + nt+cc];
    }
    __syncthreads();
    #pragma unroll
    for (int kk=0;kk<32;++kk){
      float4 a = *(const float4*)&al[kk*68+ty*4];
      float4 b = *(const float4*)&bl[kk*68+tx*4];
      acc[0][0]+=a.x*b.x; acc[0][1]+=a.x*b.y; acc[0][2]+=a.x*b.z; acc[0][3]+=a.x*b.w;
      acc[1][0]+=a.y*b.x; acc[1][1]+=a.y*b.y; acc[1][2]+=a.y*b.z; acc[1][3]+=a.y*b.w;
      acc[2][0]+=a.z*b.x; acc[2][1]+=a.z*b.y; acc[2][2]+=a.z*b.z; acc[2][3]+=a.z*b.w;
      acc[3][0]+=a.w*b.x; acc[3][1]+=a.w*b.y; acc[3][2]+=a.w*b.z; acc[3][3]+=a.w*b.w;
    }
    __syncthreads();
  }
  #pragma unroll
  for (int i=0;i<4;++i){
    int row = mt+ty*4+i;
    #pragma unroll
    for (int m=0;m<4;++m){
      int col = nt+tx*4+m;
      float v = acc[i][m];
      if (bias) v += bias[col];
      if (act==1) v = fmaxf(v,0.f);
      else if (act==2) v = (v>0.f)? v : 0.1f*v;
      C[(long)cz*zz + (long)row*N + col] = v;
    }
  }
}

// ---------------- NT GEMM with scale: C = scale * A @ B^T ----------------
__launch_bounds__(256,1)
__global__ void gemm_nt_scaled(const float* __restrict__ A, const float* __restrict__ B,
                               float* __restrict__ C, int K, float scale)
{
  __shared__ float al[32*68];
  __shared__ float bl[32*68];
  const int mt = blockIdx.x*64, nt = blockIdx.y*64;
  const int j = threadIdx.x;
  const int tx = j&15, ty = j>>4;
  float acc[4][4];
  #pragma unroll
  for (int i=0;i<4;++i){acc[i][0]=0;acc[i][1]=0;acc[i][2]=0;acc[i][3]=0;}
  for (int k0=0;k0<K;k0+=32){
    #pragma unroll
    for (int half=0; half<2; ++half){
      int idx = j + half*256;
      int r = idx>>3, kk=(idx&7)*4;
      float4 v = *(const float4*)&A[(long)(mt+r)*K + k0+kk];
      al[(kk+0)*68+r]=v.x; al[(kk+1)*68+r]=v.y; al[(kk+2)*68+r]=v.z; al[(kk+3)*68+r]=v.w;
    }
    #pragma unroll
    for (int half=0; half<2; ++half){
      int idx = j + half*256;
      int r = idx>>3, kk=(idx&7)*4;
      float4 v = *(const float4*)&B[(long)(nt+r)*K + k0+kk];
      bl[(kk+0)*68+r]=v.x; bl[(kk+1)*68+r]=v.y; bl[(kk+2)*68+r]=v.z; bl[(kk+3)*68+r]=v.w;
    }
    __syncthreads();
    #pragma unroll
    for (int kk=0;kk<32;++kk){
      float4 a = *(const float4*)&al[kk*68+ty*4];
      float4 b = *(const float4*)&bl[kk*68+tx*4];
      acc[0][0]+=a.x*b.x; acc[0][1]+=a.x*b.y; acc[0][2]+=a.x*b.z; acc[0][3]+=a.x*b.w;
      acc[1][0]+=a.y*b.x; acc[1][1]+=a.y*b.y; acc[1][2]+=a.y*b.z; acc[1][3]+=a.y*b.w;
      acc[2][0]+=a.z*b.x; acc[2][1]+=a.z*b.y; acc[2][2]+=a.z*b.z; acc[2][3]+=a.z*b.w;
      acc[3][0]+=a.w*b.x; acc[3][1]+=a.w*b.y; acc[3][2]+=a.w*b.z; acc[3][3]+=a.w*b.w;
    }
    __syncthreads();
  }
  #pragma unroll
  for (int i=0;i<4;++i){
    #pragma unroll
    for (int m=0;m<4;++m){
      C[(long)(mt+ty*4+i)*S_ + nt+tx*4+m] = acc[i][m]*scale;
    }
  }
}

// ---------------- top-k + sparse softmax-gather ----------------
__launch_bounds__(256,1)
__global__ void topk_gather(const float* __restrict__ sim, const float* __restrict__ xs,
                            const int* __restrict__ Kp, float* __restrict__ dynpre)
{
  __shared__ float row[S_];
  __shared__ float work[S_];
  __shared__ float wred[4]; __shared__ int ired[4];
  __shared__ float selw[256]; __shared__ int seli[256];
  __shared__ int cnt; __shared__ float sh_kth, sh_max, sh_den;
  const int s = blockIdx.x, j = threadIdx.x;
  const float* rp = sim + (long)s*S_;
  for (int i=j;i<S_;i+=256){ float v=rp[i]; row[i]=v; work[i]=v; }
  if (j==0) cnt=0;
  __syncthreads();
  const int K = Kp[0];
  for (int it=0; it<K; ++it){
    float m=-3.0e38f; int mi=0;
    for (int i=j;i<S_;i+=256){ float v=work[i]; if (v>m){m=v;mi=i;} }
    #pragma unroll
    for (int o=32;o>=1;o>>=1){
      float om=__shfl_xor(m,o); int oi=__shfl_xor(mi,o);
      if (om>m){m=om;mi=oi;}
    }
    if ((j&63)==0){ wred[j>>6]=m; ired[j>>6]=mi; }
    __syncthreads();
    if (j==0){
      float bm=wred[0]; int bi=ired[0];
      #pragma unroll
      for (int w=1;w<4;++w) if (wred[w]>bm){bm=wred[w];bi=ired[w];}
      work[bi]=-3.0e38f;
      if (it==0) sh_max=bm;
      sh_kth=bm;
    }
    __syncthreads();
  }
  const float kth=sh_kth, rmax=sh_max;
  for (int i=j;i<S_;i+=256){
    float v=row[i];
    if (v>=kth){
      int p=atomicAdd(&cnt,1);
      if (p<256){ seli[p]=i; selw[p]=__expf(v-rmax); }
    }
  }
  __syncthreads();
  int c = cnt; if (c>256) c=256;
  {
    float p = (j<c)? selw[j] : 0.f;
    p = warp_sum64(p);
    if ((j&63)==0) wred[j>>6]=p;
    __syncthreads();
    if (j==0) sh_den = wred[0]+wred[1]+wred[2]+wred[3];
    __syncthreads();
  }
  float acc=0.f;
  for (int l=0;l<c;++l) acc += selw[l]*xs[(long)seli[l]*D_ + j];
  dynpre[(long)s*D_+j] = acc / sh_den;
}

// ---------------- hyper = sum_n ps[n] * reps[n] ----------------
__global__ void hyperwsum_kernel(const float* __restrict__ reps, const float* __restrict__ ps,
                                 float* __restrict__ hyper)
{
  long idx = (long)blockIdx.x*256+threadIdx.x;  // grid 2048
  hyper[idx] = ps[0]*reps[idx] + ps[1]*reps[(long)SD_+idx]
             + ps[2]*reps[2L*SD_+idx] + ps[3]*reps[3L*SD_+idx];
}

// ---------------- fusion ----------------
__global__ void fuse_kernel(const float* __restrict__ xs, const float* __restrict__ dyn,
                            const float* __restrict__ hyper, const float* __restrict__ beta,
                            float* __restrict__ fused)
{
  long idx = (long)blockIdx.x*256+threadIdx.x;  // grid 2048
  float b0=beta[0],b1=beta[1],b2=beta[2];
  float mx=fmaxf(b0,fmaxf(b1,b2));
  float e0=__expf(b0-mx),e1=__expf(b1-mx),e2=__expf(b2-mx);
  float inv=1.f/(e0+e1+e2);
  fused[idx] = e0*inv*xs[idx] + e1*inv*dyn[idx] + e2*inv*hyper[idx];
}

// ---------------- head: out = hh1 @ Wm2 + bm2 ----------------
__global__ void head_kernel(const float* __restrict__ hh1, const float* __restrict__ Wm2,
                            const float* __restrict__ bm2, float* __restrict__ out)
{
  int r = blockIdx.x*32 + (threadIdx.x>>3);   // grid 64
  int sub = threadIdx.x&7;
  const float* hp = hh1 + (long)r*D_;
  float acc=0.f;
  for (int c=sub;c<D_;c+=8) acc += hp[c]*Wm2[c];
  acc += __shfl_xor(acc,1); acc += __shfl_xor(acc,2); acc += __shfl_xor(acc,4);
  if (sub==0) out[r]=acc+bm2[0];
}

// ---------------- launch ----------------
extern "C" void kernel_launch(void* const* d_in, const int* in_sizes, int n_in,
                              void* d_out, int out_size, void* d_ws, size_t ws_size,
                              hipStream_t stream)
{
  (void)in_sizes;(void)n_in;(void)out_size;(void)ws_size;
  const float* x        =(const float*)d_in[0];
  const float* snapshot =(const float*)d_in[1];
  const float* ps       =(const float*)d_in[2];
  const float* beta     =(const float*)d_in[3];
  const float* Wemb=(const float*)d_in[4];  const float* bemb=(const float*)d_in[5];
  const float* Wq  =(const float*)d_in[6];  const float* bq  =(const float*)d_in[7];
  const float* Wk  =(const float*)d_in[8];  const float* bk  =(const float*)d_in[9];
  const float* Wv  =(const float*)d_in[10]; const float* bv  =(const float*)d_in[11];
  const float* Wo  =(const float*)d_in[12]; const float* bo  =(const float*)d_in[13];
  const float* ln1g=(const float*)d_in[14]; const float* ln1b=(const float*)d_in[15];
  const float* Wint=(const float*)d_in[16]; const float* bint=(const float*)d_in[17];
  const float* Wmix=(const float*)d_in[18]; const float* bmix=(const float*)d_in[19];
  const float* ln2g=(const float*)d_in[20]; const float* ln2b=(const float*)d_in[21];
  const float* Wt  =(const float*)d_in[22]; const float* bt  =(const float*)d_in[23];
  const float* vt  =(const float*)d_in[24];
  const float* Wh1 =(const float*)d_in[25]; const float* bh1 =(const float*)d_in[26];
  const float* filt1=(const float*)d_in[27];
  const float* Wh2 =(const float*)d_in[28]; const float* bh2 =(const float*)d_in[29];
  const float* filt2=(const float*)d_in[30];
  const float* Wa  =(const float*)d_in[31]; const float* Wb  =(const float*)d_in[32];
  const float* Wg  =(const float*)d_in[33]; const float* bg  =(const float*)d_in[34];
  const float* Wm1 =(const float*)d_in[35]; const float* bm1 =(const float*)d_in[36];
  const float* Wm2 =(const float*)d_in[37]; const float* bm2 =(const float*)d_in[38];
  const int* numedges=(const int*)d_in[39];
  float* out=(float*)d_out;

  // ---- workspace layout (floats). Peak 11,674,112 floats = 44.5 MB. ----
  // region [0 .. 6431232): Ppart(4194304) Hn(1048576) HnD(1048576) P(131072) Dv(8192) De(512)
  //   overlays (time-disjoint, stream-ordered): pe(16384)@0 -> Ppart@0 -> reps(2097152)@0 -> sim(4194304)@0
  float* w = (float*)d_ws;
  float* Ppart = w;
  float* Hn    = w + 4194304;
  float* HnD   = Hn + 1048576;
  float* P     = HnD + 1048576;
  float* Dv    = P + 131072;
  float* De    = Dv + 8192;
  float* pe    = w;            // overlay (dead after stageA, before first hg_phase1)
  float* repsb = w;            // overlay (written after last hg_reduceP consumed Ppart)
  float* sim   = w;            // overlay (written after hyperwsum consumed repsb)
  float* xs    = w + 6431232;
  float* hyper = xs + SD_;
  float* bufA  = hyper + SD_;          // NS*SD = 4*SD
  float* bufB  = bufA + 4*SD_;         // NS*SD
  // tail overlays on bufA/bufB (dead after hyper stage):
  float* p1    = bufA;
  float* q1    = bufA + SD_;
  float* dynpre= bufA + 2*SD_;
  float* dyn   = bufA + 3*SD_;
  float* fused = bufB;
  float* hh1   = bufB + SD_;

  hipMemsetAsync(De, 0, (size_t)NS_*E_*sizeof(float), stream);
  pe_kernel<<<64,256,0,stream>>>(pe);
  stageA_kernel<<<S_,256,0,stream>>>(x,pe,Wemb,bemb,Wq,bq,Wk,bk,Wv,bv,Wo,bo,
                                     ln1g,ln1b,Wint,bint,Wmix,bmix,ln2g,ln2b,Wt,bt,vt,xs);
  hg_deg<<<dim3(32,NS_),256,0,stream>>>(snapshot,Dv,De);
  hg_scale<<<4096,256,0,stream>>>(snapshot,Dv,De,Hn,HnD);

  auto applyA=[&](const float* M, long mz,
                  const float* X1, long x1z, float c1,
                  const float* X2, long x2z, float c2, float c3,
                  const float* filt, int uf, float* outb){
    hg_phase1<<<dim3(KC_,NS_),256,0,stream>>>(Hn,M,mz,Ppart);
    hg_reduceP<<<dim3(8,NS_),256,0,stream>>>(Ppart,P);
    hg_phase2<<<dim3(32,4,NS_),256,0,stream>>>(HnD,P,X1,x1z,c1,X2,x2z,c2,c3,filt,uf,outb);
  };

  // ---- wavelet hypergraph conv, layer 1 (z=xs, filt1, Wh1, leaky_relu 0.1) ----
  // psi = I - L + 0.5 L^2, psi_inv = I + L + 0.5 L^2, L = I - A
  applyA(xs,0,     xs,0,1.f,    nullptr,0,0.f,  -1.f,  nullptr,0, bufA);  // t1 = L z
  applyA(bufA,SD_, xs,0,1.f,    bufA,SD_,1.5f,  -0.5f, filt1,1,   bufB);  // y0 = filt*(z+1.5t1-0.5At1)
  applyA(bufB,SD_, bufB,SD_,1.f, nullptr,0,0.f, -1.f,  nullptr,0, bufA);  // t3 = L y0
  applyA(bufA,SD_, bufB,SD_,1.f, bufA,SD_,-0.5f,-0.5f, nullptr,0, bufA);  // p = y0-0.5t3-0.5At3 (in-place X2)
  gemm_nn<<<dim3(32,4,NS_),256,0,stream>>>(bufA,SD_, Wh1,0, bufB,SD_, 256,256, bh1, 2); // r1

  // ---- layer 2 (z=r1=bufB, filt2, Wh2, no act) ----
  applyA(bufB,SD_, bufB,SD_,1.f, nullptr,0,0.f, -1.f,  nullptr,0, bufA);  // t1
  applyA(bufA,SD_, bufB,SD_,1.f, bufA,SD_,1.5f, -0.5f, filt2,1,   bufB);  // y0 (in-place X1)
  applyA(bufB,SD_, bufB,SD_,1.f, nullptr,0,0.f, -1.f,  nullptr,0, bufA);  // t3
  applyA(bufA,SD_, bufB,SD_,1.f, bufA,SD_,-0.5f,-0.5f, nullptr,0, bufA);  // p
  gemm_nn<<<dim3(32,4,NS_),256,0,stream>>>(bufA,SD_, Wh2,0, repsb,SD_, 256,256, bh2, 0); // reps -> region
  hyperwsum_kernel<<<2048,256,0,stream>>>(repsb,ps,hyper);

  // ---- dynamic graph ----
  gemm_nn<<<dim3(32,4,1),256,0,stream>>>(xs,0, Wa,0, p1,0, 256,256, nullptr, 0);
  gemm_nn<<<dim3(32,4,1),256,0,stream>>>(xs,0, Wb,0, q1,0, 256,256, nullptr, 0);
  gemm_nt_scaled<<<dim3(32,32),256,0,stream>>>(p1,q1,sim,256,0.0625f);   // sim -> region
  topk_gather<<<S_,256,0,stream>>>(sim,xs,numedges,dynpre);
  gemm_nn<<<dim3(32,4,1),256,0,stream>>>(dynpre,0, Wg,0, dyn,0, 256,256, bg, 1);

  // ---- fusion + head ----
  fuse_kernel<<<2048,256,0,stream>>>(xs,dyn,hyper,beta,fused);
  gemm_nn<<<dim3(32,4,1),256,0,stream>>>(fused,0, Wm1,0, hh1,0, 256,256, bm1, 1);
  head_kernel<<<64,256,0,stream>>>(hh1,Wm2,bm2,out);
}

// Round 3
// 3996.630 us; speedup vs baseline: 1.2079x; 1.2079x over previous
//
#include <hip/hip_runtime.h>
#include <math.h>

#define S_ 2048
#define T_ 64
#define F_ 16
#define D_ 256
#define NS_ 4
#define E_ 128
#define H_ 8
#define KC_ 32
#define SD_ (S_*D_)

// packed-weight plane offsets (shorts)
#define OFFQ 0
#define OFFK 65536
#define OFFV 131072
#define OFFO 196608
#define OFFI 262144
#define OFFT 327680
#define OFFM 393216
#define PKPLANE 524288
#define PKBASE 11674112   // float offset in ws where packed weights start

typedef __attribute__((ext_vector_type(8))) short bf16x8;
typedef __attribute__((ext_vector_type(4))) float f32x4;

// ---------------- helpers ----------------
__device__ __forceinline__ float warp_sum64(float v){
  #pragma unroll
  for (int o=32;o>=1;o>>=1) v += __shfl_xor(v,o);
  return v;
}
__device__ __forceinline__ float warp_max64(float v){
  #pragma unroll
  for (int o=32;o>=1;o>>=1) v = fmaxf(v,__shfl_xor(v,o));
  return v;
}
__device__ __forceinline__ float softplus_f(float v){
  return fmaxf(v,0.f) + log1pf(__expf(-fabsf(v)));
}
__device__ __forceinline__ float tanh_f(float v){
  float t = __expf(-2.f*fabsf(v));
  float r = (1.f-t)/(1.f+t);
  return copysignf(r, v);
}
// split fp32 into bf16 hi + bf16 lo (RNE); a ~= hi + lo with ~2^-18 residual
__device__ __forceinline__ void splitf(float f, short& h, short& l){
  unsigned u = __float_as_uint(f);
  unsigned hb = (u + 0x7FFFu + ((u>>16)&1u)) >> 16;
  float fl = f - __uint_as_float(hb<<16);
  unsigned v = __float_as_uint(fl);
  unsigned lb = (v + 0x7FFFu + ((v>>16)&1u)) >> 16;
  h = (short)hb; l = (short)lb;
}
// fp32-emulating 3-MFMA accumulate (lowest-magnitude terms first)
__device__ __forceinline__ f32x4 mfma3(bf16x8 ah, bf16x8 al, bf16x8 bh, bf16x8 bl, f32x4 c){
  c = __builtin_amdgcn_mfma_f32_16x16x32_bf16(al, bh, c, 0,0,0);
  c = __builtin_amdgcn_mfma_f32_16x16x32_bf16(ah, bl, c, 0,0,0);
  c = __builtin_amdgcn_mfma_f32_16x16x32_bf16(ah, bh, c, 0,0,0);
  return c;
}
// A-fragment from fp32 LDS: A[m=lane&15][k=(lane>>4)*8+j], rows rbase..rbase+16
__device__ __forceinline__ void afrag_f32(const float* base, int stride, int rbase, int ks, int lane, bf16x8& hi, bf16x8& lo){
  const float* p = base + (rbase + (lane&15))*stride + ks + ((lane>>4)<<3);
  #pragma unroll
  for (int jj=0;jj<8;++jj){ short h,l; splitf(p[jj],h,l); hi[jj]=h; lo[jj]=l; }
}
// B-fragment from packed global planes: contiguous 16B per lane per (ktile,ntile)
__device__ __forceinline__ void bfrag_g(const short* hp, const short* lp, int kt, int ntg, int lane, bf16x8& hi, bf16x8& lo){
  long o = (long)((kt*16+ntg)*64 + lane) * 8;
  hi = *(const bf16x8*)(hp + o);
  lo = *(const bf16x8*)(lp + o);
}
// B-fragment from packed (hi|lo<<16) uint32 LDS tiles
__device__ __forceinline__ void bfrag_pk(const unsigned* pk, int tile, int lane, bf16x8& hi, bf16x8& lo){
  const unsigned* p = pk + (((tile<<6) + lane)<<3);
  #pragma unroll
  for (int jj=0;jj<8;++jj){ unsigned u=p[jj]; hi[jj]=(short)(u & 0xffffu); lo[jj]=(short)(u>>16); }
}

// ---------------- weight packing: W(K x 256) -> fragment-ordered hi/lo planes ----------------
__global__ void pack_weights(const float* __restrict__ W, short* __restrict__ hip, short* __restrict__ lop){
  int i = blockIdx.x*256 + threadIdx.x;
  int jj = i&7, n=(i>>3)&15, q=(i>>7)&3, ntg=(i>>9)&15, kt=i>>13;
  float f = W[(kt*32 + q*8 + jj)*256 + (ntg*16 + n)];
  short h,l; splitf(f,h,l);
  hip[i]=h; lop[i]=l;
}

// ---------------- positional encoding ----------------
__global__ void pe_kernel(float* __restrict__ pe){
  int i = blockIdx.x*256 + threadIdx.x;       // grid 64 -> 16384
  int t = i >> 8, d = i & 255;
  int ii = d >> 1;
  float w = __expf(-(float)ii * (logf(10000.f)/128.f));
  float ang = (float)t * w;
  pe[i] = (d & 1) ? cosf(ang) : sinf(ang);
}

// ---------------- stage A: per-stock temporal pipeline (MFMA split-bf16) ----------------
__launch_bounds__(256,1)
__global__ void stageA_kernel(
    const float* __restrict__ x, const float* __restrict__ pe,
    const float* __restrict__ Wemb, const float* __restrict__ bemb,
    const float* __restrict__ bq, const float* __restrict__ bk, const float* __restrict__ bv,
    const float* __restrict__ bo,
    const float* __restrict__ ln1g, const float* __restrict__ ln1b,
    const float* __restrict__ bint,
    const float* __restrict__ bmix,
    const float* __restrict__ ln2g, const float* __restrict__ ln2b,
    const float* __restrict__ bt,
    const float* __restrict__ vt,
    const short* __restrict__ pwh, const short* __restrict__ pwl,
    float* __restrict__ xs)
{
  __shared__ float hbuf[T_][D_];     // 64KB
  __shared__ float aux[16384];       // 64KB multipurpose
  __shared__ float smallb[2*T_];

  float* qbuf = aux;                       // [64][36] fp32 (q, later o_h)
  unsigned* k2f = (unsigned*)(aux + 2304); // 2048 u32: K B-frags (hi|lo)
  unsigned* v2f = (unsigned*)(aux + 4352); // 2048 u32: V B-frags
  float* scb   = aux + 6400;               // [64][68] fp32 probs

  const int j  = threadIdx.x;
  const int s  = blockIdx.x;
  const int w  = j >> 6;      // wave id; owns rows w*16..+16
  const int lane = j & 63;
  const int m_ = lane & 15, qd = lane >> 4;
  const int rg = w, c0 = lane;

  // ---- stage x[s] into aux ----
  {
    const float* xp = x + (long)s*T_*F_;
    for (int i=j; i<T_*F_; i+=256) aux[i] = xp[i];
  }
  __syncthreads();

  // ---- embedding + PE (vector, K=16) ----
  {
    float acc[16][4];
    #pragma unroll
    for (int r=0;r<16;++r){acc[r][0]=0;acc[r][1]=0;acc[r][2]=0;acc[r][3]=0;}
    #pragma unroll
    for (int k=0;k<F_;++k){
      float w0=Wemb[k*D_+c0], w1=Wemb[k*D_+c0+64], w2=Wemb[k*D_+c0+128], w3=Wemb[k*D_+c0+192];
      #pragma unroll
      for (int r=0;r<16;++r){
        float hv = aux[(rg*16+r)*F_+k];
        acc[r][0]+=hv*w0; acc[r][1]+=hv*w1; acc[r][2]+=hv*w2; acc[r][3]+=hv*w3;
      }
    }
    float b0=bemb[c0],b1=bemb[c0+64],b2=bemb[c0+128],b3=bemb[c0+192];
    __syncthreads();  // x-stage reads done before later aux writes
    #pragma unroll
    for (int r=0;r<16;++r){
      int t = rg*16+r;
      hbuf[t][c0]     = acc[r][0]+b0+pe[t*D_+c0];
      hbuf[t][c0+64]  = acc[r][1]+b1+pe[t*D_+c0+64];
      hbuf[t][c0+128] = acc[r][2]+b2+pe[t*D_+c0+128];
      hbuf[t][c0+192] = acc[r][3]+b3+pe[t*D_+c0+192];
    }
  }
  __syncthreads();

  // ---- hoist A-fragments of h (per-wave rows) for QKV ----
  bf16x8 AH[8], AL[8];
  #pragma unroll
  for (int kt=0;kt<8;++kt) afrag_f32(&hbuf[0][0], D_, w*16, kt*32, lane, AH[kt], AL[kt]);

  const float rs = 0.17677669529663687f;  // 1/sqrt(32)
  f32x4 co[16];
  #pragma unroll
  for (int nt=0;nt<16;++nt) co[nt] = (f32x4){0.f,0.f,0.f,0.f};

  for (int hh=0; hh<H_; ++hh){
    // ---- QKV via MFMA (N=32 each) ----
    f32x4 qa[2],ka[2],va[2];
    #pragma unroll
    for (int nt=0;nt<2;++nt){
      qa[nt]=(f32x4){0.f,0.f,0.f,0.f};
      ka[nt]=(f32x4){0.f,0.f,0.f,0.f};
      va[nt]=(f32x4){0.f,0.f,0.f,0.f};
    }
    #pragma unroll
    for (int kt=0;kt<8;++kt){
      #pragma unroll
      for (int nt=0;nt<2;++nt){
        bf16x8 bh,bl;
        bfrag_g(pwh+OFFQ, pwl+OFFQ, kt, hh*2+nt, lane, bh, bl);
        qa[nt]=mfma3(AH[kt],AL[kt],bh,bl,qa[nt]);
        bfrag_g(pwh+OFFK, pwl+OFFK, kt, hh*2+nt, lane, bh, bl);
        ka[nt]=mfma3(AH[kt],AL[kt],bh,bl,ka[nt]);
        bfrag_g(pwh+OFFV, pwl+OFFV, kt, hh*2+nt, lane, bh, bl);
        va[nt]=mfma3(AH[kt],AL[kt],bh,bl,va[nt]);
      }
    }
    // epilogue: q -> qbuf fp32 (scaled); k,v -> packed B-fragment LDS
    #pragma unroll
    for (int nt=0;nt<2;++nt){
      #pragma unroll
      for (int r=0;r<4;++r){
        int t = w*16 + qd*4 + r;
        int cp = nt*16 + m_;
        int col = hh*32 + cp;
        qbuf[t*36+cp] = (qa[nt][r]+bq[col])*rs;
        short h,l;
        float kv = ka[nt][r]+bk[col];
        splitf(kv,h,l);
        k2f[(((t>>4)*4 + (cp>>3))*16 + (t&15))*8 + (cp&7)] =
            (unsigned)(unsigned short)h | ((unsigned)(unsigned short)l<<16);
        float vv = va[nt][r]+bv[col];
        splitf(vv,h,l);
        v2f[((((t>>5)*2 + (cp>>4))*4 + ((t>>3)&3))*16 + (cp&15))*8 + (t&7)] =
            (unsigned)(unsigned short)h | ((unsigned)(unsigned short)l<<16);
      }
    }
    __syncthreads();   // k2f/v2f visible to all waves
    // ---- scores = q @ k^T (M=16 own rows, N=64 keys, K=32) ----
    bf16x8 ah,al;
    afrag_f32(qbuf, 36, w*16, 0, lane, ah, al);
    f32x4 sc4[4];
    #pragma unroll
    for (int nt=0;nt<4;++nt){
      bf16x8 bh,bl; bfrag_pk(k2f, nt, lane, bh, bl);
      sc4[nt] = mfma3(ah,al,bh,bl,(f32x4){0.f,0.f,0.f,0.f});
    }
    // softmax over 64 keys, in registers (row spread over 16 lanes x 4 regs)
    #pragma unroll
    for (int r=0;r<4;++r){
      float mx = fmaxf(fmaxf(sc4[0][r],sc4[1][r]),fmaxf(sc4[2][r],sc4[3][r]));
      #pragma unroll
      for (int o=8;o>=1;o>>=1) mx = fmaxf(mx, __shfl_xor(mx,o));
      float es = 0.f;
      #pragma unroll
      for (int nt=0;nt<4;++nt){ float e=__expf(sc4[nt][r]-mx); sc4[nt][r]=e; es+=e; }
      #pragma unroll
      for (int o=8;o>=1;o>>=1) es += __shfl_xor(es,o);
      float inv = 1.f/es;
      int t = w*16 + qd*4 + r;
      #pragma unroll
      for (int nt=0;nt<4;++nt) scb[t*68 + nt*16 + m_] = sc4[nt][r]*inv;
    }
    // ---- o_h = P @ V (M=16, N=32, K=64) ----
    f32x4 oa[2];
    oa[0]=(f32x4){0.f,0.f,0.f,0.f}; oa[1]=(f32x4){0.f,0.f,0.f,0.f};
    #pragma unroll
    for (int kt=0;kt<2;++kt){
      bf16x8 ah2,al2; afrag_f32(scb, 68, w*16, kt*32, lane, ah2, al2);
      #pragma unroll
      for (int nt=0;nt<2;++nt){
        bf16x8 bh,bl; bfrag_pk(v2f, kt*2+nt, lane, bh, bl);
        oa[nt]=mfma3(ah2,al2,bh,bl,oa[nt]);
      }
    }
    #pragma unroll
    for (int nt=0;nt<2;++nt){
      #pragma unroll
      for (int r=0;r<4;++r)
        qbuf[(w*16+qd*4+r)*36 + nt*16+m_] = oa[nt][r];   // overwrite q with o_h
    }
    // ---- accumulate o_h @ Wo[hh-block] into co ----
    bf16x8 aoh,aol; afrag_f32(qbuf, 36, w*16, 0, lane, aoh, aol);
    #pragma unroll
    for (int nt=0;nt<16;++nt){
      bf16x8 bh,bl; bfrag_g(pwh+OFFO, pwl+OFFO, hh, nt, lane, bh, bl);
      co[nt]=mfma3(aoh,aol,bh,bl,co[nt]);
    }
    __syncthreads();   // protect k2f/v2f for next head
  }

  // ---- residual + bo ----
  #pragma unroll
  for (int nt=0;nt<16;++nt){
    int cc = nt*16+m_;
    float bov = bo[cc];
    #pragma unroll
    for (int r=0;r<4;++r)
      hbuf[w*16+qd*4+r][cc] += co[nt][r] + bov;
  }
  __syncthreads();

  // ---- LN1 (vector) ----
  {
    float g0=ln1g[c0],g1=ln1g[c0+64],g2=ln1g[c0+128],g3=ln1g[c0+192];
    float bb0=ln1b[c0],bb1=ln1b[c0+64],bb2=ln1b[c0+128],bb3=ln1b[c0+192];
    for (int rr=0;rr<16;++rr){
      int t=rg*16+rr;
      float v0=hbuf[t][c0],v1=hbuf[t][c0+64],v2=hbuf[t][c0+128],v3=hbuf[t][c0+192];
      float sm=warp_sum64(v0+v1+v2+v3);
      float sq=warp_sum64(v0*v0+v1*v1+v2*v2+v3*v3);
      float mean=sm*(1.f/256.f);
      float inv=rsqrtf(fmaxf(sq*(1.f/256.f)-mean*mean,0.f)+1e-5f);
      hbuf[t][c0]    =(v0-mean)*inv*g0+bb0;
      hbuf[t][c0+64] =(v1-mean)*inv*g1+bb1;
      hbuf[t][c0+128]=(v2-mean)*inv*g2+bb2;
      hbuf[t][c0+192]=(v3-mean)*inv*g3+bb3;
    }
  }
  __syncthreads();

  // ---- intensity = softplus(h @ Wint + bint) -> aux (MFMA) ----
  {
    f32x4 ai[16];
    #pragma unroll
    for (int nt=0;nt<16;++nt) ai[nt]=(f32x4){0.f,0.f,0.f,0.f};
    #pragma unroll
    for (int kt=0;kt<8;++kt){
      bf16x8 ah,al; afrag_f32(&hbuf[0][0], D_, w*16, kt*32, lane, ah, al);
      #pragma unroll
      for (int nt=0;nt<16;++nt){
        bf16x8 bh,bl; bfrag_g(pwh+OFFI, pwl+OFFI, kt, nt, lane, bh, bl);
        ai[nt]=mfma3(ah,al,bh,bl,ai[nt]);
      }
    }
    #pragma unroll
    for (int nt=0;nt<16;++nt){
      int cc = nt*16+m_;
      float bb = bint[cc];
      #pragma unroll
      for (int r=0;r<4;++r){
        int t = w*16+qd*4+r;
        aux[t*256+cc] = softplus_f(ai[nt][r]+bb);
      }
    }
  }

  // ---- z = relu([h|intensity] @ Wmix + bmix) -> hbuf (MFMA, K=512) ----
  {
    f32x4 az[16];
    #pragma unroll
    for (int nt=0;nt<16;++nt) az[nt]=(f32x4){0.f,0.f,0.f,0.f};
    #pragma unroll
    for (int kt=0;kt<16;++kt){
      bf16x8 ah,al;
      if (kt<8) afrag_f32(&hbuf[0][0], D_, w*16, kt*32, lane, ah, al);
      else      afrag_f32(aux,          D_, w*16, (kt-8)*32, lane, ah, al);
      #pragma unroll
      for (int nt=0;nt<16;++nt){
        bf16x8 bh,bl; bfrag_g(pwh+OFFM, pwl+OFFM, kt, nt, lane, bh, bl);
        az[nt]=mfma3(ah,al,bh,bl,az[nt]);
      }
    }
    #pragma unroll
    for (int nt=0;nt<16;++nt){
      int cc = nt*16+m_;
      float bb = bmix[cc];
      #pragma unroll
      for (int r=0;r<4;++r){
        int t = w*16+qd*4+r;
        hbuf[t][cc] = fmaxf(az[nt][r]+bb,0.f);
      }
    }
  }

  // ---- LN2 (vector) ----
  {
    float g0=ln2g[c0],g1=ln2g[c0+64],g2=ln2g[c0+128],g3=ln2g[c0+192];
    float bb0=ln2b[c0],bb1=ln2b[c0+64],bb2=ln2b[c0+128],bb3=ln2b[c0+192];
    for (int rr=0;rr<16;++rr){
      int t=rg*16+rr;
      float v0=hbuf[t][c0],v1=hbuf[t][c0+64],v2=hbuf[t][c0+128],v3=hbuf[t][c0+192];
      float sm=warp_sum64(v0+v1+v2+v3);
      float sq=warp_sum64(v0*v0+v1*v1+v2*v2+v3*v3);
      float mean=sm*(1.f/256.f);
      float inv=rsqrtf(fmaxf(sq*(1.f/256.f)-mean*mean,0.f)+1e-5f);
      hbuf[t][c0]    =(v0-mean)*inv*g0+bb0;
      hbuf[t][c0+64] =(v1-mean)*inv*g1+bb1;
      hbuf[t][c0+128]=(v2-mean)*inv*g2+bb2;
      hbuf[t][c0+192]=(v3-mean)*inv*g3+bb3;
    }
  }

  // ---- u = tanh(h @ Wt + bt) -> aux (MFMA) ----
  {
    f32x4 at4[16];
    #pragma unroll
    for (int nt=0;nt<16;++nt) at4[nt]=(f32x4){0.f,0.f,0.f,0.f};
    #pragma unroll
    for (int kt=0;kt<8;++kt){
      bf16x8 ah,al; afrag_f32(&hbuf[0][0], D_, w*16, kt*32, lane, ah, al);
      #pragma unroll
      for (int nt=0;nt<16;++nt){
        bf16x8 bh,bl; bfrag_g(pwh+OFFT, pwl+OFFT, kt, nt, lane, bh, bl);
        at4[nt]=mfma3(ah,al,bh,bl,at4[nt]);
      }
    }
    #pragma unroll
    for (int nt=0;nt<16;++nt){
      int cc = nt*16+m_;
      float bb = bt[cc];
      #pragma unroll
      for (int r=0;r<4;++r){
        int t = w*16+qd*4+r;
        aux[t*256+cc] = tanh_f(at4[nt][r]+bb);
      }
    }
  }

  // ---- temporal attention pooling ----
  {
    float vt0=vt[c0],vt1=vt[c0+64],vt2=vt[c0+128],vt3=vt[c0+192];
    for (int rr=0;rr<16;++rr){
      int t=rg*16+rr;
      float p = aux[t*256+c0]*vt0+aux[t*256+c0+64]*vt1+aux[t*256+c0+128]*vt2+aux[t*256+c0+192]*vt3;
      p = warp_sum64(p);
      if (c0==0) smallb[t]=p;
    }
  }
  __syncthreads();
  if (j < 64){
    float v = smallb[j];
    float m = warp_max64(v);
    float e = __expf(v-m);
    float ssum = warp_sum64(e);
    smallb[64+j] = e/ssum;
  }
  __syncthreads();
  {
    float acc=0.f;
    #pragma unroll 8
    for (int t=0;t<T_;++t) acc += smallb[64+t]*hbuf[t][j];
    xs[(long)s*D_+j] = acc;
  }
}

// ---------------- hypergraph prep ----------------
__global__ void hg_deg(const float* __restrict__ Hinc, float* __restrict__ Dv, float* __restrict__ De){
  const int n = blockIdx.y, s0 = blockIdx.x*64;   // grid (32, NS)
  const float* Hp = Hinc + (long)n*S_*E_;
  const int j = threadIdx.x;
  {
    int r = j>>2, q = j&3;
    const float* rp = Hp + (long)(s0+r)*E_ + q*32;
    float sm=0;
    #pragma unroll
    for (int e=0;e<32;++e) sm += rp[e];
    sm += __shfl_xor(sm,1); sm += __shfl_xor(sm,2);
    if (q==0) Dv[n*S_+s0+r]=sm+1e-6f;
  }
  if (j < E_){
    float cs=0;
    for (int ss=0;ss<64;++ss) cs += Hp[(long)(s0+ss)*E_+j];
    atomicAdd(&De[n*E_+j], cs);   // integer-valued fp32 adds: exact, deterministic
  }
}

__global__ void hg_scale(const float* __restrict__ Hinc, const float* __restrict__ Dv,
                         const float* __restrict__ De, float* __restrict__ Hn, float* __restrict__ HnD){
  long i = (long)blockIdx.x*256+threadIdx.x;   // grid 4096
  int n = (int)(i >> 18);
  int rem = (int)(i & 262143);
  int srow = rem >> 7;
  int e = rem & 127;
  float h = Hinc[i];
  float hn = h * rsqrtf(Dv[n*S_+srow]);
  Hn[i] = hn;
  HnD[i] = hn / (De[n*E_+e]+1e-6f);
}

// P-partial: Ppart[n][kc] = Hn_chunk^T @ M_chunk  (chunk = 64 rows of S)
__launch_bounds__(256,1)
__global__ void hg_phase1(const float* __restrict__ Hn, const float* __restrict__ M,
                          long mz, float* __restrict__ Ppart)
{
  __shared__ float hl[64*E_];
  __shared__ float ml[64*D_];
  const int kc = blockIdx.x, n = blockIdx.y;
  const int j = threadIdx.x;
  const float* Hp = Hn + ((long)n*S_ + (long)kc*64)*E_;
  const float* Mp = M + (long)n*mz + (long)kc*64*D_;
  for (int i=j*4; i<64*E_; i+=1024) *(float4*)&hl[i] = *(const float4*)&Hp[i];
  for (int i=j*4; i<64*D_; i+=1024) *(float4*)&ml[i] = *(const float4*)&Mp[i];
  __syncthreads();
  const int eg = j & 15, dg = j >> 4;
  float acc[8][16];
  #pragma unroll
  for (int e=0;e<8;++e){
    #pragma unroll
    for (int d=0;d<16;++d) acc[e][d]=0.f;
  }
  for (int ss=0; ss<64; ++ss){
    float hv[8], mv[16];
    *(float4*)&hv[0] = *(const float4*)&hl[ss*E_+eg*8];
    *(float4*)&hv[4] = *(const float4*)&hl[ss*E_+eg*8+4];
    *(float4*)&mv[0]  = *(const float4*)&ml[ss*D_+dg*16];
    *(float4*)&mv[4]  = *(const float4*)&ml[ss*D_+dg*16+4];
    *(float4*)&mv[8]  = *(const float4*)&ml[ss*D_+dg*16+8];
    *(float4*)&mv[12] = *(const float4*)&ml[ss*D_+dg*16+12];
    #pragma unroll
    for (int e=0;e<8;++e){
      #pragma unroll
      for (int d=0;d<16;++d) acc[e][d] += hv[e]*mv[d];
    }
  }
  float* Pp = Ppart + (long)(n*KC_+kc)*E_*D_;
  #pragma unroll
  for (int e=0;e<8;++e){
    int erow = eg*8+e;
    #pragma unroll
    for (int d4=0;d4<16;d4+=4){
      float4 v = make_float4(acc[e][d4],acc[e][d4+1],acc[e][d4+2],acc[e][d4+3]);
      *(float4*)&Pp[(long)erow*D_ + dg*16 + d4] = v;
    }
  }
}

__global__ void hg_reduceP(const float* __restrict__ Ppart, float* __restrict__ P){
  const int n = blockIdx.y;
  int base = blockIdx.x*4096;    // grid (8, NS)
  for (int i = base + threadIdx.x; i < base+4096; i += 256){
    const float* pp = Ppart + (long)n*KC_*E_*D_ + i;
    float a = 0;
    #pragma unroll
    for (int kc=0;kc<KC_;++kc) a += pp[(long)kc*E_*D_];
    P[(long)n*E_*D_ + i] = a;
  }
}

// out = filt * (c1*X1 + c2*X2 + c3*(HnD @ P)); in-place safe vs X1/X2
__launch_bounds__(256,1)
__global__ void hg_phase2(const float* __restrict__ HnD, const float* __restrict__ P,
                          const float* __restrict__ X1, long x1z, float c1,
                          const float* __restrict__ X2, long x2z, float c2,
                          float c3, const float* __restrict__ filt, int usefilt,
                          float* __restrict__ out)
{
  __shared__ float al[E_*68];
  __shared__ float pl[E_*68];
  const int st = blockIdx.x*64, dt = blockIdx.y*64, n = blockIdx.z;
  const int j = threadIdx.x;
  {
    const int r = j >> 2, k0 = (j&3)*32;
    const float* hp = HnD + ((long)n*S_ + st + r)*E_ + k0;
    #pragma unroll
    for (int kk=0; kk<32; kk+=4){
      float4 v = *(const float4*)&hp[kk];
      al[(k0+kk+0)*68+r]=v.x;
      al[(k0+kk+1)*68+r]=v.y;
      al[(k0+kk+2)*68+r]=v.z;
      al[(k0+kk+3)*68+r]=v.w;
    }
  }
  for (int idx=j; idx<E_*16; idx+=256){
    int k = idx>>4, dsub = (idx&15)*4;
    *(float4*)&pl[k*68+dsub] = *(const float4*)&P[((long)n*E_+k)*D_ + dt + dsub];
  }
  __syncthreads();
  const int tx = j&15, ty = j>>4;
  float acc[4][4];
  #pragma unroll
  for (int i=0;i<4;++i){acc[i][0]=0;acc[i][1]=0;acc[i][2]=0;acc[i][3]=0;}
  for (int k=0;k<E_;++k){
    float4 a = *(const float4*)&al[k*68+ty*4];
    float4 b = *(const float4*)&pl[k*68+tx*4];
    acc[0][0]+=a.x*b.x; acc[0][1]+=a.x*b.y; acc[0][2]+=a.x*b.z; acc[0][3]+=a.x*b.w;
    acc[1][0]+=a.y*b.x; acc[1][1]+=a.y*b.y; acc[1][2]+=a.y*b.z; acc[1][3]+=a.y*b.w;
    acc[2][0]+=a.z*b.x; acc[2][1]+=a.z*b.y; acc[2][2]+=a.z*b.z; acc[2][3]+=a.z*b.w;
    acc[3][0]+=a.w*b.x; acc[3][1]+=a.w*b.y; acc[3][2]+=a.w*b.z; acc[3][3]+=a.w*b.w;
  }
  #pragma unroll
  for (int i=0;i<4;++i){
    int srow = st + ty*4 + i;
    float f = usefilt ? filt[srow] : 1.f;
    #pragma unroll
    for (int m=0;m<4;++m){
      int d = dt + tx*4+m;
      long li = (long)srow*D_ + d;
      float v = c3*acc[i][m];
      if (X1) v += c1*X1[x1z*n + li];
      if (X2) v += c2*X2[x2z*n + li];
      out[((long)n*S_ + srow)*D_ + d] = f*v;
    }
  }
}

// ---------------- generic fp32 GEMM (NN), 64x64 tile ----------------
__launch_bounds__(256,1)
__global__ void gemm_nn(const float* __restrict__ A, long az,
                        const float* __restrict__ B, long bz,
                        float* __restrict__ C, long cz,
                        int K, int N,
                        const float* __restrict__ bias, int act)
{
  __shared__ float al[32*68];
  __shared__ float bl[32*68];
  const int mt = blockIdx.x*64, nt = blockIdx.y*64, zz = blockIdx.z;
  const int j = threadIdx.x;
  const float* Ap = A + (long)az*zz;
  const float* Bp = B + (long)bz*zz;
  const int tx = j&15, ty = j>>4;
  float acc[4][4];
  #pragma unroll
  for (int i=0;i<4;++i){acc[i][0]=0;acc[i][1]=0;acc[i][2]=0;acc[i][3]=0;}
  for (int k0=0;k0<K;k0+=32){
    #pragma unroll
    for (int half=0; half<2; ++half){
      int idx = j + half*256;
      int r = idx>>3, kk=(idx&7)*4;
      float4 v = *(const float4*)&Ap[(long)(mt+r)*K + k0+kk];
      al[(kk+0)*68+r]=v.x; al[(kk+1)*68+r]=v.y; al[(kk+2)*68+r]=v.z; al[(kk+3)*68+r]=v.w;
    }
    #pragma unroll
    for (int half=0; half<2; ++half){
      int idx = j + half*256;
      int r = idx>>4, cc=(idx&15)*4;
      *(float4*)&bl[r*68+cc] = *(const float4*)&Bp[(long)(k0+r)*N + nt+cc];
    }
    __syncthreads();
    #pragma unroll
    for (int kk=0;kk<32;++kk){
      float4 a = *(const float4*)&al[kk*68+ty*4];
      float4 b = *(const float4*)&bl[kk*68+tx*4];
      acc[0][0]+=a.x*b.x; acc[0][1]+=a.x*b.y; acc[0][2]+=a.x*b.z; acc[0][3]+=a.x*b.w;
      acc[1][0]+=a.y*b.x; acc[1][1]+=a.y*b.y; acc[1][2]+=a.y*b.z; acc[1][3]+=a.y*b.w;
      acc[2][0]+=a.z*b.x; acc[2][1]+=a.z*b.y; acc[2][2]+=a.z*b.z; acc[2][3]+=a.z*b.w;
      acc[3][0]+=a.w*b.x; acc[3][1]+=a.w*b.y; acc[3][2]+=a.w*b.z; acc[3][3]+=a.w*b.w;
    }
    __syncthreads();
  }
  #pragma unroll
  for (int i=0;i<4;++i){
    int row = mt+ty*4+i;
    #pragma unroll
    for (int m=0;m<4;++m){
      int col = nt+tx*4+m;
      float v = acc[i][m];
      if (bias) v += bias[col];
      if (act==1) v = fmaxf(v,0.f);
      else if (act==2) v = (v>0.f)? v : 0.1f*v;
      C[(long)cz*zz + (long)row*N + col] = v;
    }
  }
}

// ---------------- NT GEMM with scale: C = scale * A @ B^T ----------------
__launch_bounds__(256,1)
__global__ void gemm_nt_scaled(const float* __restrict__ A, const float* __restrict__ B,
                               float* __restrict__ C, int K, float scale)
{
  __shared__ float al[32*68];
  __shared__ float bl[32*68];
  const int mt = blockIdx.x*64, nt = blockIdx.y*64;
  const int j = threadIdx.x;
  const int tx = j&15, ty = j>>4;
  float acc[4][4];
  #pragma unroll
  for (int i=0;i<4;++i){acc[i][0]=0;acc[i][1]=0;acc[i][2]=0;acc[i][3]=0;}
  for (int k0=0;k0<K;k0+=32){
    #pragma unroll
    for (int half=0; half<2; ++half){
      int idx = j + half*256;
      int r = idx>>3, kk=(idx&7)*4;
      float4 v = *(const float4*)&A[(long)(mt+r)*K + k0+kk];
      al[(kk+0)*68+r]=v.x; al[(kk+1)*68+r]=v.y; al[(kk+2)*68+r]=v.z; al[(kk+3)*68+r]=v.w;
    }
    #pragma unroll
    for (int half=0; half<2; ++half){
      int idx = j + half*256;
      int r = idx>>3, kk=(idx&7)*4;
      float4 v = *(const float4*)&B[(long)(nt+r)*K + k0+kk];
      bl[(kk+0)*68+r]=v.x; bl[(kk+1)*68+r]=v.y; bl[(kk+2)*68+r]=v.z; bl[(kk+3)*68+r]=v.w;
    }
    __syncthreads();
    #pragma unroll
    for (int kk=0;kk<32;++kk){
      float4 a = *(const float4*)&al[kk*68+ty*4];
      float4 b = *(const float4*)&bl[kk*68+tx*4];
      acc[0][0]+=a.x*b.x; acc[0][1]+=a.x*b.y; acc[0][2]+=a.x*b.z; acc[0][3]+=a.x*b.w;
      acc[1][0]+=a.y*b.x; acc[1][1]+=a.y*b.y; acc[1][2]+=a.y*b.z; acc[1][3]+=a.y*b.w;
      acc[2][0]+=a.z*b.x; acc[2][1]+=a.z*b.y; acc[2][2]+=a.z*b.z; acc[2][3]+=a.z*b.w;
      acc[3][0]+=a.w*b.x; acc[3][1]+=a.w*b.y; acc[3][2]+=a.w*b.z; acc[3][3]+=a.w*b.w;
    }
    __syncthreads();
  }
  #pragma unroll
  for (int i=0;i<4;++i){
    #pragma unroll
    for (int m=0;m<4;++m){
      C[(long)(mt+ty*4+i)*S_ + nt+tx*4+m] = acc[i][m]*scale;
    }
  }
}

// ---------------- top-k + sparse softmax-gather ----------------
__launch_bounds__(256,1)
__global__ void topk_gather(const float* __restrict__ sim, const float* __restrict__ xs,
                            const int* __restrict__ Kp, float* __restrict__ dynpre)
{
  __shared__ float row[S_];
  __shared__ float work[S_];
  __shared__ float wred[4]; __shared__ int ired[4];
  __shared__ float selw[256]; __shared__ int seli[256];
  __shared__ int cnt; __shared__ float sh_kth, sh_max, sh_den;
  const int s = blockIdx.x, j = threadIdx.x;
  const float* rp = sim + (long)s*S_;
  for (int i=j;i<S_;i+=256){ float v=rp[i]; row[i]=v; work[i]=v; }
  if (j==0) cnt=0;
  __syncthreads();
  const int K = Kp[0];
  for (int it=0; it<K; ++it){
    float m=-3.0e38f; int mi=0;
    for (int i=j;i<S_;i+=256){ float v=work[i]; if (v>m){m=v;mi=i;} }
    #pragma unroll
    for (int o=32;o>=1;o>>=1){
      float om=__shfl_xor(m,o); int oi=__shfl_xor(mi,o);
      if (om>m){m=om;mi=oi;}
    }
    if ((j&63)==0){ wred[j>>6]=m; ired[j>>6]=mi; }
    __syncthreads();
    if (j==0){
      float bm=wred[0]; int bi=ired[0];
      #pragma unroll
      for (int w=1;w<4;++w) if (wred[w]>bm){bm=wred[w];bi=ired[w];}
      work[bi]=-3.0e38f;
      if (it==0) sh_max=bm;
      sh_kth=bm;
    }
    __syncthreads();
  }
  const float kth=sh_kth, rmax=sh_max;
  for (int i=j;i<S_;i+=256){
    float v=row[i];
    if (v>=kth){
      int p=atomicAdd(&cnt,1);
      if (p<256){ seli[p]=i; selw[p]=__expf(v-rmax); }
    }
  }
  __syncthreads();
  int c = cnt; if (c>256) c=256;
  {
    float p = (j<c)? selw[j] : 0.f;
    p = warp_sum64(p);
    if ((j&63)==0) wred[j>>6]=p;
    __syncthreads();
    if (j==0) sh_den = wred[0]+wred[1]+wred[2]+wred[3];
    __syncthreads();
  }
  float acc=0.f;
  for (int l=0;l<c;++l) acc += selw[l]*xs[(long)seli[l]*D_ + j];
  dynpre[(long)s*D_+j] = acc / sh_den;
}

// ---------------- hyper = sum_n ps[n] * reps[n] ----------------
__global__ void hyperwsum_kernel(const float* __restrict__ reps, const float* __restrict__ ps,
                                 float* __restrict__ hyper)
{
  long idx = (long)blockIdx.x*256+threadIdx.x;  // grid 2048
  hyper[idx] = ps[0]*reps[idx] + ps[1]*reps[(long)SD_+idx]
             + ps[2]*reps[2L*SD_+idx] + ps[3]*reps[3L*SD_+idx];
}

// ---------------- fusion ----------------
__global__ void fuse_kernel(const float* __restrict__ xs, const float* __restrict__ dyn,
                            const float* __restrict__ hyper, const float* __restrict__ beta,
                            float* __restrict__ fused)
{
  long idx = (long)blockIdx.x*256+threadIdx.x;  // grid 2048
  float b0=beta[0],b1=beta[1],b2=beta[2];
  float mx=fmaxf(b0,fmaxf(b1,b2));
  float e0=__expf(b0-mx),e1=__expf(b1-mx),e2=__expf(b2-mx);
  float inv=1.f/(e0+e1+e2);
  fused[idx] = e0*inv*xs[idx] + e1*inv*dyn[idx] + e2*inv*hyper[idx];
}

// ---------------- head: out = hh1 @ Wm2 + bm2 ----------------
__global__ void head_kernel(const float* __restrict__ hh1, const float* __restrict__ Wm2,
                            const float* __restrict__ bm2, float* __restrict__ out)
{
  int r = blockIdx.x*32 + (threadIdx.x>>3);   // grid 64
  int sub = threadIdx.x&7;
  const float* hp = hh1 + (long)r*D_;
  float acc=0.f;
  for (int c=sub;c<D_;c+=8) acc += hp[c]*Wm2[c];
  acc += __shfl_xor(acc,1); acc += __shfl_xor(acc,2); acc += __shfl_xor(acc,4);
  if (sub==0) out[r]=acc+bm2[0];
}

// ---------------- launch ----------------
extern "C" void kernel_launch(void* const* d_in, const int* in_sizes, int n_in,
                              void* d_out, int out_size, void* d_ws, size_t ws_size,
                              hipStream_t stream)
{
  (void)in_sizes;(void)n_in;(void)out_size;(void)ws_size;
  const float* x        =(const float*)d_in[0];
  const float* snapshot =(const float*)d_in[1];
  const float* ps       =(const float*)d_in[2];
  const float* beta     =(const float*)d_in[3];
  const float* Wemb=(const float*)d_in[4];  const float* bemb=(const float*)d_in[5];
  const float* Wq  =(const float*)d_in[6];  const float* bq  =(const float*)d_in[7];
  const float* Wk  =(const float*)d_in[8];  const float* bk  =(const float*)d_in[9];
  const float* Wv  =(const float*)d_in[10]; const float* bv  =(const float*)d_in[11];
  const float* Wo  =(const float*)d_in[12]; const float* bo  =(const float*)d_in[13];
  const float* ln1g=(const float*)d_in[14]; const float* ln1b=(const float*)d_in[15];
  const float* Wint=(const float*)d_in[16]; const float* bint=(const float*)d_in[17];
  const float* Wmix=(const float*)d_in[18]; const float* bmix=(const float*)d_in[19];
  const float* ln2g=(const float*)d_in[20]; const float* ln2b=(const float*)d_in[21];
  const float* Wt  =(const float*)d_in[22]; const float* bt  =(const float*)d_in[23];
  const float* vt  =(const float*)d_in[24];
  const float* Wh1 =(const float*)d_in[25]; const float* bh1 =(const float*)d_in[26];
  const float* filt1=(const float*)d_in[27];
  const float* Wh2 =(const float*)d_in[28]; const float* bh2 =(const float*)d_in[29];
  const float* filt2=(const float*)d_in[30];
  const float* Wa  =(const float*)d_in[31]; const float* Wb  =(const float*)d_in[32];
  const float* Wg  =(const float*)d_in[33]; const float* bg  =(const float*)d_in[34];
  const float* Wm1 =(const float*)d_in[35]; const float* bm1 =(const float*)d_in[36];
  const float* Wm2 =(const float*)d_in[37]; const float* bm2 =(const float*)d_in[38];
  const int* numedges=(const int*)d_in[39];
  float* out=(float*)d_out;

  // ---- workspace layout (floats). Peak ~46.6 MB. ----
  float* w = (float*)d_ws;
  float* Ppart = w;
  float* Hn    = w + 4194304;
  float* HnD   = Hn + 1048576;
  float* P     = HnD + 1048576;
  float* Dv    = P + 131072;
  float* De    = Dv + 8192;
  float* pe    = w;            // overlay (dead before first hg_phase1)
  float* repsb = w;            // overlay (after Ppart consumed)
  float* sim   = w;            // overlay (after repsb consumed)
  float* xs    = w + 6431232;
  float* hyper = xs + SD_;
  float* bufA  = hyper + SD_;          // NS*SD
  float* bufB  = bufA + 4*SD_;         // NS*SD
  float* p1    = bufA;
  float* q1    = bufA + SD_;
  float* dynpre= bufA + 2*SD_;
  float* dyn   = bufA + 3*SD_;
  float* fused = bufB;
  float* hh1   = bufB + SD_;
  short* pwh   = (short*)(w + PKBASE);
  short* pwl   = pwh + PKPLANE;

  hipMemsetAsync(De, 0, (size_t)NS_*E_*sizeof(float), stream);
  pe_kernel<<<64,256,0,stream>>>(pe);
  pack_weights<<<256,256,0,stream>>>(Wq,   pwh+OFFQ, pwl+OFFQ);
  pack_weights<<<256,256,0,stream>>>(Wk,   pwh+OFFK, pwl+OFFK);
  pack_weights<<<256,256,0,stream>>>(Wv,   pwh+OFFV, pwl+OFFV);
  pack_weights<<<256,256,0,stream>>>(Wo,   pwh+OFFO, pwl+OFFO);
  pack_weights<<<256,256,0,stream>>>(Wint, pwh+OFFI, pwl+OFFI);
  pack_weights<<<256,256,0,stream>>>(Wt,   pwh+OFFT, pwl+OFFT);
  pack_weights<<<512,256,0,stream>>>(Wmix, pwh+OFFM, pwl+OFFM);

  stageA_kernel<<<S_,256,0,stream>>>(x,pe,Wemb,bemb,bq,bk,bv,bo,
                                     ln1g,ln1b,bint,bmix,ln2g,ln2b,bt,vt,
                                     pwh,pwl,xs);
  hg_deg<<<dim3(32,NS_),256,0,stream>>>(snapshot,Dv,De);
  hg_scale<<<4096,256,0,stream>>>(snapshot,Dv,De,Hn,HnD);

  auto applyA=[&](const float* M, long mz,
                  const float* X1, long x1z, float c1,
                  const float* X2, long x2z, float c2, float c3,
                  const float* filt, int uf, float* outb){
    hg_phase1<<<dim3(KC_,NS_),256,0,stream>>>(Hn,M,mz,Ppart);
    hg_reduceP<<<dim3(8,NS_),256,0,stream>>>(Ppart,P);
    hg_phase2<<<dim3(32,4,NS_),256,0,stream>>>(HnD,P,X1,x1z,c1,X2,x2z,c2,c3,filt,uf,outb);
  };

  // ---- wavelet hypergraph conv, layer 1 ----
  applyA(xs,0,     xs,0,1.f,    nullptr,0,0.f,  -1.f,  nullptr,0, bufA);  // t1 = L z
  applyA(bufA,SD_, xs,0,1.f,    bufA,SD_,1.5f,  -0.5f, filt1,1,   bufB);  // y0
  applyA(bufB,SD_, bufB,SD_,1.f, nullptr,0,0.f, -1.f,  nullptr,0, bufA);  // t3
  applyA(bufA,SD_, bufB,SD_,1.f, bufA,SD_,-0.5f,-0.5f, nullptr,0, bufA);  // p
  gemm_nn<<<dim3(32,4,NS_),256,0,stream>>>(bufA,SD_, Wh1,0, bufB,SD_, 256,256, bh1, 2);

  // ---- layer 2 ----
  applyA(bufB,SD_, bufB,SD_,1.f, nullptr,0,0.f, -1.f,  nullptr,0, bufA);
  applyA(bufA,SD_, bufB,SD_,1.f, bufA,SD_,1.5f, -0.5f, filt2,1,   bufB);
  applyA(bufB,SD_, bufB,SD_,1.f, nullptr,0,0.f, -1.f,  nullptr,0, bufA);
  applyA(bufA,SD_, bufB,SD_,1.f, bufA,SD_,-0.5f,-0.5f, nullptr,0, bufA);
  gemm_nn<<<dim3(32,4,NS_),256,0,stream>>>(bufA,SD_, Wh2,0, repsb,SD_, 256,256, bh2, 0);
  hyperwsum_kernel<<<2048,256,0,stream>>>(repsb,ps,hyper);

  // ---- dynamic graph ----
  gemm_nn<<<dim3(32,4,1),256,0,stream>>>(xs,0, Wa,0, p1,0, 256,256, nullptr, 0);
  gemm_nn<<<dim3(32,4,1),256,0,stream>>>(xs,0, Wb,0, q1,0, 256,256, nullptr, 0);
  gemm_nt_scaled<<<dim3(32,32),256,0,stream>>>(p1,q1,sim,256,0.0625f);
  topk_gather<<<S_,256,0,stream>>>(sim,xs,numedges,dynpre);
  gemm_nn<<<dim3(32,4,1),256,0,stream>>>(dynpre,0, Wg,0, dyn,0, 256,256, bg, 1);

  // ---- fusion + head ----
  fuse_kernel<<<2048,256,0,stream>>>(xs,dyn,hyper,beta,fused);
  gemm_nn<<<dim3(32,4,1),256,0,stream>>>(fused,0, Wm1,0, hh1,0, 256,256, bm1, 1);
  head_kernel<<<64,256,0,stream>>>(hh1,Wm2,bm2,out);
}

// Round 4
// 1862.294 us; speedup vs baseline: 2.5922x; 2.1461x over previous
//
#include <hip/hip_runtime.h>
#include <math.h>

#define S_ 2048
#define T_ 64
#define F_ 16
#define D_ 256
#define NS_ 4
#define E_ 128
#define H_ 8
#define KC_ 32
#define SD_ (S_*D_)
#define HS 260   // hbuf row stride (pad +4: 2-way LDS conflict = free)

// packed-weight plane offsets (shorts)
#define OFFQ 0
#define OFFK 65536
#define OFFV 131072
#define OFFO 196608
#define OFFI 262144
#define OFFT 327680
#define OFFM 393216
#define PKPLANE 524288
#define PKBASE 11674112   // float offset in ws where packed weights start

typedef __attribute__((ext_vector_type(8))) short bf16x8;
typedef __attribute__((ext_vector_type(4))) float f32x4;

// ---------------- helpers ----------------
__device__ __forceinline__ float warp_sum64(float v){
  #pragma unroll
  for (int o=32;o>=1;o>>=1) v += __shfl_xor(v,o);
  return v;
}
__device__ __forceinline__ float warp_max64(float v){
  #pragma unroll
  for (int o=32;o>=1;o>>=1) v = fmaxf(v,__shfl_xor(v,o));
  return v;
}
__device__ __forceinline__ float softplus_f(float v){
  return fmaxf(v,0.f) + log1pf(__expf(-fabsf(v)));
}
__device__ __forceinline__ float tanh_f(float v){
  float t = __expf(-2.f*fabsf(v));
  float r = (1.f-t)/(1.f+t);
  return copysignf(r, v);
}
// split fp32 into bf16 hi + bf16 lo (RNE); a ~= hi + lo with ~2^-18 residual
__device__ __forceinline__ void splitf(float f, short& h, short& l){
  unsigned u = __float_as_uint(f);
  unsigned hb = (u + 0x7FFFu + ((u>>16)&1u)) >> 16;
  float fl = f - __uint_as_float(hb<<16);
  unsigned v = __float_as_uint(fl);
  unsigned lb = (v + 0x7FFFu + ((v>>16)&1u)) >> 16;
  h = (short)hb; l = (short)lb;
}
// fp32-emulating 3-MFMA accumulate (lowest-magnitude terms first)
__device__ __forceinline__ f32x4 mfma3(bf16x8 ah, bf16x8 al, bf16x8 bh, bf16x8 bl, f32x4 c){
  c = __builtin_amdgcn_mfma_f32_16x16x32_bf16(al, bh, c, 0,0,0);
  c = __builtin_amdgcn_mfma_f32_16x16x32_bf16(ah, bl, c, 0,0,0);
  c = __builtin_amdgcn_mfma_f32_16x16x32_bf16(ah, bh, c, 0,0,0);
  return c;
}
// A-fragment from fp32 LDS: A[m=lane&15][k=(lane>>4)*8+j]
__device__ __forceinline__ void afrag_f32(const float* base, int stride, int rbase, int ks, int lane, bf16x8& hi, bf16x8& lo){
  const float* p = base + (rbase + (lane&15))*stride + ks + ((lane>>4)<<3);
  #pragma unroll
  for (int jj=0;jj<8;++jj){ short h,l; splitf(p[jj],h,l); hi[jj]=h; lo[jj]=l; }
}
// B-fragment from packed (hi|lo<<16) uint32 LDS tiles
__device__ __forceinline__ void bfrag_pk(const unsigned* pk, int tile, int lane, bf16x8& hi, bf16x8& lo){
  const unsigned* p = pk + (((tile<<6) + lane)<<3);
  #pragma unroll
  for (int jj=0;jj<8;++jj){ unsigned u=p[jj]; hi[jj]=(short)(u & 0xffffu); lo[jj]=(short)(u>>16); }
}

// ---------------- weight packing: W(K x 256) -> fragment-ordered hi/lo planes ----------------
__global__ void pack_weights(const float* __restrict__ W, short* __restrict__ hip, short* __restrict__ lop){
  int i = blockIdx.x*256 + threadIdx.x;
  int jj = i&7, n=(i>>3)&15, q=(i>>7)&3, ntg=(i>>9)&15, kt=i>>13;
  float f = W[(kt*32 + q*8 + jj)*256 + (ntg*16 + n)];
  short h,l; splitf(f,h,l);
  hip[i]=h; lop[i]=l;
}

// ---------------- positional encoding ----------------
__global__ void pe_kernel(float* __restrict__ pe){
  int i = blockIdx.x*256 + threadIdx.x;       // grid 64 -> 16384
  int t = i >> 8, d = i & 255;
  int ii = d >> 1;
  float w = __expf(-(float)ii * (logf(10000.f)/128.f));
  float ang = (float)t * w;
  pe[i] = (d & 1) ? cosf(ang) : sinf(ang);
}

// ---------------- stage A: LDS-staged weight-stationary MFMA pipeline ----------------
// LDS: hbuf 66560 + smem 92672 = 159232 B -> 1 block/CU
__launch_bounds__(256,1)
__global__ void stageA_kernel(
    const float* __restrict__ x, const float* __restrict__ pe,
    const float* __restrict__ Wemb, const float* __restrict__ bemb,
    const float* __restrict__ bq, const float* __restrict__ bk, const float* __restrict__ bv,
    const float* __restrict__ bo,
    const float* __restrict__ ln1g, const float* __restrict__ ln1b,
    const float* __restrict__ bint,
    const float* __restrict__ bmix,
    const float* __restrict__ ln2g, const float* __restrict__ ln2b,
    const float* __restrict__ bt,
    const float* __restrict__ vt,
    const short* __restrict__ pwh, const short* __restrict__ pwl,
    float* __restrict__ xs)
{
  __shared__ float hbuf[T_][HS];     // 66560 B
  __shared__ char  smem[92672];

  short*    wst   = (short*)smem;                 // staging: <=24KB (attn) / <=32KB (post)
  unsigned* k2f2  = (unsigned*)(smem + 24576);    // 2 heads x 2048 u32 (16KB)
  unsigned* v2f2  = (unsigned*)(smem + 40960);    // 16KB
  float*    qb2   = (float*)(smem + 57344);       // [64][68] q / o_h (17408B)
  float*    scb   = (float*)(smem + 74752);       // [64][68] probs (17408B)
  float*    smallb= (float*)(smem + 92160);       // 128 floats

  const int j  = threadIdx.x;
  const int s  = blockIdx.x;
  const int w  = j >> 6;      // wave id; owns rows w*16..+16
  const int lane = j & 63;
  const int m_ = lane & 15, qd = lane >> 4;
  const int rg = w, c0 = lane;

  // ---- stage x[s] into smem ----
  {
    float* xb = (float*)smem;
    const float* xp = x + (long)s*T_*F_;
    for (int i=j; i<T_*F_; i+=256) xb[i] = xp[i];
  }
  __syncthreads();

  // ---- embedding + PE (vector, K=16) ----
  {
    const float* xb = (const float*)smem;
    float acc[16][4];
    #pragma unroll
    for (int r=0;r<16;++r){acc[r][0]=0;acc[r][1]=0;acc[r][2]=0;acc[r][3]=0;}
    #pragma unroll
    for (int k=0;k<F_;++k){
      float w0=Wemb[k*D_+c0], w1=Wemb[k*D_+c0+64], w2=Wemb[k*D_+c0+128], w3=Wemb[k*D_+c0+192];
      #pragma unroll
      for (int r=0;r<16;++r){
        float hv = xb[(rg*16+r)*F_+k];
        acc[r][0]+=hv*w0; acc[r][1]+=hv*w1; acc[r][2]+=hv*w2; acc[r][3]+=hv*w3;
      }
    }
    float b0=bemb[c0],b1=bemb[c0+64],b2=bemb[c0+128],b3=bemb[c0+192];
    #pragma unroll
    for (int r=0;r<16;++r){
      int t = rg*16+r;
      hbuf[t][c0]     = acc[r][0]+b0+pe[t*D_+c0];
      hbuf[t][c0+64]  = acc[r][1]+b1+pe[t*D_+c0+64];
      hbuf[t][c0+128] = acc[r][2]+b2+pe[t*D_+c0+128];
      hbuf[t][c0+192] = acc[r][3]+b3+pe[t*D_+c0+192];
    }
  }
  // own-rows write; staging barrier below synchronizes smem reuse

  const float rs = 0.17677669529663687f;  // 1/sqrt(32)
  f32x4 co[16];
  #pragma unroll
  for (int nt=0;nt<16;++nt) co[nt] = (f32x4){0.f,0.f,0.f,0.f};

  // ---- attention: head pairs ----
  for (int hp=0; hp<4; ++hp){
    f32x4 qa[4],ka[4],va[4];
    #pragma unroll
    for (int nt=0;nt<4;++nt){
      qa[nt]=(f32x4){0.f,0.f,0.f,0.f};
      ka[nt]=(f32x4){0.f,0.f,0.f,0.f};
      va[nt]=(f32x4){0.f,0.f,0.f,0.f};
    }
    for (int kt=0; kt<8; ++kt){
      __syncthreads();                                  // prior wst consumers done
      {
        int fb = (kt*16 + hp*4)*512;
        const short* srcs[6] = {pwh+OFFQ+fb, pwl+OFFQ+fb, pwh+OFFK+fb,
                                pwl+OFFK+fb, pwh+OFFV+fb, pwl+OFFV+fb};
        #pragma unroll
        for (int r=0;r<6;++r)
          *(bf16x8*)(wst + r*2048 + j*8) = *(const bf16x8*)(srcs[r] + j*8);
      }
      __syncthreads();                                  // tile ready
      bf16x8 ah, al; afrag_f32(&hbuf[0][0], HS, w*16, kt*32, lane, ah, al);
      #pragma unroll
      for (int nt=0;nt<4;++nt){
        bf16x8 bh,bl;
        bh = *(bf16x8*)(wst +            nt*512 + lane*8);
        bl = *(bf16x8*)(wst + 2048     + nt*512 + lane*8);
        qa[nt]=mfma3(ah,al,bh,bl,qa[nt]);
        bh = *(bf16x8*)(wst + 4096     + nt*512 + lane*8);
        bl = *(bf16x8*)(wst + 6144     + nt*512 + lane*8);
        ka[nt]=mfma3(ah,al,bh,bl,ka[nt]);
        bh = *(bf16x8*)(wst + 8192     + nt*512 + lane*8);
        bl = *(bf16x8*)(wst + 10240    + nt*512 + lane*8);
        va[nt]=mfma3(ah,al,bh,bl,va[nt]);
      }
    }
    // epilogue: q->qb2 (scaled), k/v -> packed B-frag LDS
    #pragma unroll
    for (int nt=0;nt<4;++nt){
      #pragma unroll
      for (int r=0;r<4;++r){
        int t = w*16 + qd*4 + r;
        int pcp = nt*16 + m_;
        int head = pcp >> 5;
        int cp = pcp & 31;
        int col = hp*64 + pcp;
        qb2[t*68 + pcp] = (qa[nt][r] + bq[col]) * rs;
        short hS,lS;
        float kv = ka[nt][r] + bk[col];
        splitf(kv,hS,lS);
        k2f2[head*2048 + (((t>>4)*4 + (cp>>3))*16 + (t&15))*8 + (cp&7)]
            = (unsigned)(unsigned short)hS | ((unsigned)(unsigned short)lS<<16);
        float vv = va[nt][r] + bv[col];
        splitf(vv,hS,lS);
        v2f2[head*2048 + ((((t>>5)*2 + (cp>>4))*4 + ((t>>3)&3))*16 + (cp&15))*8 + (t&7)]
            = (unsigned)(unsigned short)hS | ((unsigned)(unsigned short)lS<<16);
      }
    }
    __syncthreads();                                    // k2f2/v2f2 visible
    // scores + softmax + PV per head in pair (wave-private rows, no barriers)
    for (int h=0; h<2; ++h){
      bf16x8 ah,al;
      afrag_f32(qb2, 68, w*16, h*32, lane, ah, al);
      f32x4 sc4[4];
      #pragma unroll
      for (int nt=0;nt<4;++nt){
        bf16x8 bh,bl; bfrag_pk(k2f2 + h*2048, nt, lane, bh, bl);
        sc4[nt] = mfma3(ah,al,bh,bl,(f32x4){0.f,0.f,0.f,0.f});
      }
      #pragma unroll
      for (int r=0;r<4;++r){
        float mx = fmaxf(fmaxf(sc4[0][r],sc4[1][r]),fmaxf(sc4[2][r],sc4[3][r]));
        #pragma unroll
        for (int o=8;o>=1;o>>=1) mx = fmaxf(mx, __shfl_xor(mx,o));
        float es = 0.f;
        #pragma unroll
        for (int nt=0;nt<4;++nt){ float e=__expf(sc4[nt][r]-mx); sc4[nt][r]=e; es+=e; }
        #pragma unroll
        for (int o=8;o>=1;o>>=1) es += __shfl_xor(es,o);
        float inv = 1.f/es;
        int t = w*16 + qd*4 + r;
        #pragma unroll
        for (int nt=0;nt<4;++nt) scb[t*68 + nt*16 + m_] = sc4[nt][r]*inv;
      }
      f32x4 oa[2];
      oa[0]=(f32x4){0.f,0.f,0.f,0.f}; oa[1]=(f32x4){0.f,0.f,0.f,0.f};
      #pragma unroll
      for (int kt=0;kt<2;++kt){
        bf16x8 ah2,al2; afrag_f32(scb, 68, w*16, kt*32, lane, ah2, al2);
        #pragma unroll
        for (int nt=0;nt<2;++nt){
          bf16x8 bh,bl; bfrag_pk(v2f2 + h*2048, kt*2+nt, lane, bh, bl);
          oa[nt]=mfma3(ah2,al2,bh,bl,oa[nt]);
        }
      }
      #pragma unroll
      for (int nt=0;nt<2;++nt){
        #pragma unroll
        for (int r=0;r<4;++r)
          qb2[(w*16+qd*4+r)*68 + h*32 + nt*16 + m_] = oa[nt][r];  // overwrite q of head h
      }
    }
    // ---- Wo accumulate: co += o_pair @ Wo[rows hp*64..+64] ----
    for (int ks=0; ks<2; ++ks){
      bf16x8 ah,al; afrag_f32(qb2, 68, w*16, ks*32, lane, ah, al);
      for (int nh=0; nh<2; ++nh){
        __syncthreads();
        {
          int fb = ((hp*2+ks)*16 + nh*8)*512;
          #pragma unroll
          for (int r=0;r<2;++r){
            *(bf16x8*)(wst +        r*2048 + j*8) = *(const bf16x8*)(pwh+OFFO+fb + r*2048 + j*8);
            *(bf16x8*)(wst + 4096 + r*2048 + j*8) = *(const bf16x8*)(pwl+OFFO+fb + r*2048 + j*8);
          }
        }
        __syncthreads();
        #pragma unroll
        for (int nt=0; nt<8; ++nt){
          bf16x8 bh = *(bf16x8*)(wst +        nt*512 + lane*8);
          bf16x8 bl = *(bf16x8*)(wst + 4096 + nt*512 + lane*8);
          co[nh*8+nt] = mfma3(ah,al,bh,bl,co[nh*8+nt]);
        }
      }
    }
  }

  // ---- residual + bo (own rows) ----
  #pragma unroll
  for (int nt=0;nt<16;++nt){
    int cc = nt*16+m_;
    float bov = bo[cc];
    #pragma unroll
    for (int r=0;r<4;++r)
      hbuf[w*16+qd*4+r][cc] += co[nt][r] + bov;
  }

  // ---- LN1 (own rows) ----
  {
    float g0=ln1g[c0],g1=ln1g[c0+64],g2=ln1g[c0+128],g3=ln1g[c0+192];
    float bb0=ln1b[c0],bb1=ln1b[c0+64],bb2=ln1b[c0+128],bb3=ln1b[c0+192];
    for (int rr=0;rr<16;++rr){
      int t=rg*16+rr;
      float v0=hbuf[t][c0],v1=hbuf[t][c0+64],v2=hbuf[t][c0+128],v3=hbuf[t][c0+192];
      float sm=warp_sum64(v0+v1+v2+v3);
      float sq=warp_sum64(v0*v0+v1*v1+v2*v2+v3*v3);
      float mean=sm*(1.f/256.f);
      float inv=rsqrtf(fmaxf(sq*(1.f/256.f)-mean*mean,0.f)+1e-5f);
      hbuf[t][c0]    =(v0-mean)*inv*g0+bb0;
      hbuf[t][c0+64] =(v1-mean)*inv*g1+bb1;
      hbuf[t][c0+128]=(v2-mean)*inv*g2+bb2;
      hbuf[t][c0+192]=(v3-mean)*inv*g3+bb3;
    }
  }

  // ---- Wmix part1 (A = h, kt 0..7) ----
  f32x4 az[16];
  #pragma unroll
  for (int nt=0;nt<16;++nt) az[nt]=(f32x4){0.f,0.f,0.f,0.f};
  for (int kt=0; kt<8; ++kt){
    __syncthreads();
    {
      const short* hi = pwh+OFFM+kt*8192; const short* lo = pwl+OFFM+kt*8192;
      #pragma unroll
      for (int r=0;r<4;++r){
        *(bf16x8*)(wst +        r*2048 + j*8) = *(const bf16x8*)(hi + r*2048 + j*8);
        *(bf16x8*)(wst + 8192 + r*2048 + j*8) = *(const bf16x8*)(lo + r*2048 + j*8);
      }
    }
    __syncthreads();
    bf16x8 ah,al; afrag_f32(&hbuf[0][0], HS, w*16, kt*32, lane, ah, al);
    #pragma unroll
    for (int nt=0;nt<16;++nt){
      bf16x8 bh = *(bf16x8*)(wst +        nt*512 + lane*8);
      bf16x8 bl = *(bf16x8*)(wst + 8192 + nt*512 + lane*8);
      az[nt]=mfma3(ah,al,bh,bl,az[nt]);
    }
  }

  // ---- Wint: intensity (A = h) ----
  {
    f32x4 ai[16];
    #pragma unroll
    for (int nt=0;nt<16;++nt) ai[nt]=(f32x4){0.f,0.f,0.f,0.f};
    for (int kt=0; kt<8; ++kt){
      __syncthreads();
      {
        const short* hi = pwh+OFFI+kt*8192; const short* lo = pwl+OFFI+kt*8192;
        #pragma unroll
        for (int r=0;r<4;++r){
          *(bf16x8*)(wst +        r*2048 + j*8) = *(const bf16x8*)(hi + r*2048 + j*8);
          *(bf16x8*)(wst + 8192 + r*2048 + j*8) = *(const bf16x8*)(lo + r*2048 + j*8);
        }
      }
      __syncthreads();
      bf16x8 ah,al; afrag_f32(&hbuf[0][0], HS, w*16, kt*32, lane, ah, al);
      #pragma unroll
      for (int nt=0;nt<16;++nt){
        bf16x8 bh = *(bf16x8*)(wst +        nt*512 + lane*8);
        bf16x8 bl = *(bf16x8*)(wst + 8192 + nt*512 + lane*8);
        ai[nt]=mfma3(ah,al,bh,bl,ai[nt]);
      }
    }
    // write intensity into hbuf own rows (h fully consumed)
    #pragma unroll
    for (int nt=0;nt<16;++nt){
      int cc = nt*16+m_;
      float bb = bint[cc];
      #pragma unroll
      for (int r=0;r<4;++r)
        hbuf[w*16+qd*4+r][cc] = softplus_f(ai[nt][r]+bb);
    }
  }

  // ---- Wmix part2 (A = intensity, kt 8..15) ----
  for (int kt=0; kt<8; ++kt){
    __syncthreads();
    {
      const short* hi = pwh+OFFM+(8+kt)*8192; const short* lo = pwl+OFFM+(8+kt)*8192;
      #pragma unroll
      for (int r=0;r<4;++r){
        *(bf16x8*)(wst +        r*2048 + j*8) = *(const bf16x8*)(hi + r*2048 + j*8);
        *(bf16x8*)(wst + 8192 + r*2048 + j*8) = *(const bf16x8*)(lo + r*2048 + j*8);
      }
    }
    __syncthreads();
    bf16x8 ah,al; afrag_f32(&hbuf[0][0], HS, w*16, kt*32, lane, ah, al);
    #pragma unroll
    for (int nt=0;nt<16;++nt){
      bf16x8 bh = *(bf16x8*)(wst +        nt*512 + lane*8);
      bf16x8 bl = *(bf16x8*)(wst + 8192 + nt*512 + lane*8);
      az[nt]=mfma3(ah,al,bh,bl,az[nt]);
    }
  }
  // z = relu(az+bmix) -> hbuf (own rows)
  #pragma unroll
  for (int nt=0;nt<16;++nt){
    int cc = nt*16+m_;
    float bb = bmix[cc];
    #pragma unroll
    for (int r=0;r<4;++r)
      hbuf[w*16+qd*4+r][cc] = fmaxf(az[nt][r]+bb,0.f);
  }

  // ---- LN2 (own rows) ----
  {
    float g0=ln2g[c0],g1=ln2g[c0+64],g2=ln2g[c0+128],g3=ln2g[c0+192];
    float bb0=ln2b[c0],bb1=ln2b[c0+64],bb2=ln2b[c0+128],bb3=ln2b[c0+192];
    for (int rr=0;rr<16;++rr){
      int t=rg*16+rr;
      float v0=hbuf[t][c0],v1=hbuf[t][c0+64],v2=hbuf[t][c0+128],v3=hbuf[t][c0+192];
      float sm=warp_sum64(v0+v1+v2+v3);
      float sq=warp_sum64(v0*v0+v1*v1+v2*v2+v3*v3);
      float mean=sm*(1.f/256.f);
      float inv=rsqrtf(fmaxf(sq*(1.f/256.f)-mean*mean,0.f)+1e-5f);
      hbuf[t][c0]    =(v0-mean)*inv*g0+bb0;
      hbuf[t][c0+64] =(v1-mean)*inv*g1+bb1;
      hbuf[t][c0+128]=(v2-mean)*inv*g2+bb2;
      hbuf[t][c0+192]=(v3-mean)*inv*g3+bb3;
    }
  }

  // ---- Wt: u = tanh(h@Wt+bt), pooled in-register ----
  {
    f32x4 at4[16];
    #pragma unroll
    for (int nt=0;nt<16;++nt) at4[nt]=(f32x4){0.f,0.f,0.f,0.f};
    for (int kt=0; kt<8; ++kt){
      __syncthreads();
      {
        const short* hi = pwh+OFFT+kt*8192; const short* lo = pwl+OFFT+kt*8192;
        #pragma unroll
        for (int r=0;r<4;++r){
          *(bf16x8*)(wst +        r*2048 + j*8) = *(const bf16x8*)(hi + r*2048 + j*8);
          *(bf16x8*)(wst + 8192 + r*2048 + j*8) = *(const bf16x8*)(lo + r*2048 + j*8);
        }
      }
      __syncthreads();
      bf16x8 ah,al; afrag_f32(&hbuf[0][0], HS, w*16, kt*32, lane, ah, al);
      #pragma unroll
      for (int nt=0;nt<16;++nt){
        bf16x8 bh = *(bf16x8*)(wst +        nt*512 + lane*8);
        bf16x8 bl = *(bf16x8*)(wst + 8192 + nt*512 + lane*8);
        at4[nt]=mfma3(ah,al,bh,bl,at4[nt]);
      }
    }
    float pr[4] = {0.f,0.f,0.f,0.f};
    #pragma unroll
    for (int nt=0;nt<16;++nt){
      int cc = nt*16+m_;
      float btc = bt[cc], vtc = vt[cc];
      #pragma unroll
      for (int r=0;r<4;++r) pr[r] += tanh_f(at4[nt][r]+btc)*vtc;
    }
    #pragma unroll
    for (int r=0;r<4;++r){
      float p = pr[r];
      p += __shfl_xor(p,1); p += __shfl_xor(p,2);
      p += __shfl_xor(p,4); p += __shfl_xor(p,8);
      if (m_==0) smallb[w*16+qd*4+r] = p;
    }
  }
  __syncthreads();
  if (j < 64){
    float v = smallb[j];
    float m = warp_max64(v);
    float e = __expf(v-m);
    float ssum = warp_sum64(e);
    smallb[64+j] = e/ssum;
  }
  __syncthreads();
  {
    float acc=0.f;
    #pragma unroll 8
    for (int t=0;t<T_;++t) acc += smallb[64+t]*hbuf[t][j];
    xs[(long)s*D_+j] = acc;
  }
}

// ---------------- hypergraph prep ----------------
__global__ void hg_deg(const float* __restrict__ Hinc, float* __restrict__ Dv, float* __restrict__ De){
  const int n = blockIdx.y, s0 = blockIdx.x*64;   // grid (32, NS)
  const float* Hp = Hinc + (long)n*S_*E_;
  const int j = threadIdx.x;
  {
    int r = j>>2, q = j&3;
    const float* rp = Hp + (long)(s0+r)*E_ + q*32;
    float sm=0;
    #pragma unroll
    for (int e=0;e<32;++e) sm += rp[e];
    sm += __shfl_xor(sm,1); sm += __shfl_xor(sm,2);
    if (q==0) Dv[n*S_+s0+r]=sm+1e-6f;
  }
  if (j < E_){
    float cs=0;
    for (int ss=0;ss<64;++ss) cs += Hp[(long)(s0+ss)*E_+j];
    atomicAdd(&De[n*E_+j], cs);   // integer-valued fp32 adds: exact, deterministic
  }
}

__global__ void hg_scale(const float* __restrict__ Hinc, const float* __restrict__ Dv,
                         const float* __restrict__ De, float* __restrict__ Hn, float* __restrict__ HnD){
  long i = (long)blockIdx.x*256+threadIdx.x;   // grid 4096
  int n = (int)(i >> 18);
  int rem = (int)(i & 262143);
  int srow = rem >> 7;
  int e = rem & 127;
  float h = Hinc[i];
  float hn = h * rsqrtf(Dv[n*S_+srow]);
  Hn[i] = hn;
  HnD[i] = hn / (De[n*E_+e]+1e-6f);
}

// P-partial: Ppart[n][kc] = Hn_chunk^T @ M_chunk  (chunk = 64 rows of S)
__launch_bounds__(256,1)
__global__ void hg_phase1(const float* __restrict__ Hn, const float* __restrict__ M,
                          long mz, float* __restrict__ Ppart)
{
  __shared__ float hl[64*E_];
  __shared__ float ml[64*D_];
  const int kc = blockIdx.x, n = blockIdx.y;
  const int j = threadIdx.x;
  const float* Hp = Hn + ((long)n*S_ + (long)kc*64)*E_;
  const float* Mp = M + (long)n*mz + (long)kc*64*D_;
  for (int i=j*4; i<64*E_; i+=1024) *(float4*)&hl[i] = *(const float4*)&Hp[i];
  for (int i=j*4; i<64*D_; i+=1024) *(float4*)&ml[i] = *(const float4*)&Mp[i];
  __syncthreads();
  const int eg = j & 15, dg = j >> 4;
  float acc[8][16];
  #pragma unroll
  for (int e=0;e<8;++e){
    #pragma unroll
    for (int d=0;d<16;++d) acc[e][d]=0.f;
  }
  for (int ss=0; ss<64; ++ss){
    float hv[8], mv[16];
    *(float4*)&hv[0] = *(const float4*)&hl[ss*E_+eg*8];
    *(float4*)&hv[4] = *(const float4*)&hl[ss*E_+eg*8+4];
    *(float4*)&mv[0]  = *(const float4*)&ml[ss*D_+dg*16];
    *(float4*)&mv[4]  = *(const float4*)&ml[ss*D_+dg*16+4];
    *(float4*)&mv[8]  = *(const float4*)&ml[ss*D_+dg*16+8];
    *(float4*)&mv[12] = *(const float4*)&ml[ss*D_+dg*16+12];
    #pragma unroll
    for (int e=0;e<8;++e){
      #pragma unroll
      for (int d=0;d<16;++d) acc[e][d] += hv[e]*mv[d];
    }
  }
  float* Pp = Ppart + (long)(n*KC_+kc)*E_*D_;
  #pragma unroll
  for (int e=0;e<8;++e){
    int erow = eg*8+e;
    #pragma unroll
    for (int d4=0;d4<16;d4+=4){
      float4 v = make_float4(acc[e][d4],acc[e][d4+1],acc[e][d4+2],acc[e][d4+3]);
      *(float4*)&Pp[(long)erow*D_ + dg*16 + d4] = v;
    }
  }
}

__global__ void hg_reduceP(const float* __restrict__ Ppart, float* __restrict__ P){
  const int n = blockIdx.y;
  int base = blockIdx.x*4096;    // grid (8, NS)
  for (int i = base + threadIdx.x; i < base+4096; i += 256){
    const float* pp = Ppart + (long)n*KC_*E_*D_ + i;
    float a = 0;
    #pragma unroll
    for (int kc=0;kc<KC_;++kc) a += pp[(long)kc*E_*D_];
    P[(long)n*E_*D_ + i] = a;
  }
}

// out = filt * (c1*X1 + c2*X2 + c3*(HnD @ P)); in-place safe vs X1/X2
__launch_bounds__(256,1)
__global__ void hg_phase2(const float* __restrict__ HnD, const float* __restrict__ P,
                          const float* __restrict__ X1, long x1z, float c1,
                          const float* __restrict__ X2, long x2z, float c2,
                          float c3, const float* __restrict__ filt, int usefilt,
                          float* __restrict__ out)
{
  __shared__ float al[E_*68];
  __shared__ float pl[E_*68];
  const int st = blockIdx.x*64, dt = blockIdx.y*64, n = blockIdx.z;
  const int j = threadIdx.x;
  {
    const int r = j >> 2, k0 = (j&3)*32;
    const float* hp = HnD + ((long)n*S_ + st + r)*E_ + k0;
    #pragma unroll
    for (int kk=0; kk<32; kk+=4){
      float4 v = *(const float4*)&hp[kk];
      al[(k0+kk+0)*68+r]=v.x;
      al[(k0+kk+1)*68+r]=v.y;
      al[(k0+kk+2)*68+r]=v.z;
      al[(k0+kk+3)*68+r]=v.w;
    }
  }
  for (int idx=j; idx<E_*16; idx+=256){
    int k = idx>>4, dsub = (idx&15)*4;
    *(float4*)&pl[k*68+dsub] = *(const float4*)&P[((long)n*E_+k)*D_ + dt + dsub];
  }
  __syncthreads();
  const int tx = j&15, ty = j>>4;
  float acc[4][4];
  #pragma unroll
  for (int i=0;i<4;++i){acc[i][0]=0;acc[i][1]=0;acc[i][2]=0;acc[i][3]=0;}
  for (int k=0;k<E_;++k){
    float4 a = *(const float4*)&al[k*68+ty*4];
    float4 b = *(const float4*)&pl[k*68+tx*4];
    acc[0][0]+=a.x*b.x; acc[0][1]+=a.x*b.y; acc[0][2]+=a.x*b.z; acc[0][3]+=a.x*b.w;
    acc[1][0]+=a.y*b.x; acc[1][1]+=a.y*b.y; acc[1][2]+=a.y*b.z; acc[1][3]+=a.y*b.w;
    acc[2][0]+=a.z*b.x; acc[2][1]+=a.z*b.y; acc[2][2]+=a.z*b.z; acc[2][3]+=a.z*b.w;
    acc[3][0]+=a.w*b.x; acc[3][1]+=a.w*b.y; acc[3][2]+=a.w*b.z; acc[3][3]+=a.w*b.w;
  }
  #pragma unroll
  for (int i=0;i<4;++i){
    int srow = st + ty*4 + i;
    float f = usefilt ? filt[srow] : 1.f;
    #pragma unroll
    for (int m=0;m<4;++m){
      int d = dt + tx*4+m;
      long li = (long)srow*D_ + d;
      float v = c3*acc[i][m];
      if (X1) v += c1*X1[x1z*n + li];
      if (X2) v += c2*X2[x2z*n + li];
      out[((long)n*S_ + srow)*D_ + d] = f*v;
    }
  }
}

// ---------------- generic fp32 GEMM (NN), 64x64 tile ----------------
__launch_bounds__(256,1)
__global__ void gemm_nn(const float* __restrict__ A, long az,
                        const float* __restrict__ B, long bz,
                        float* __restrict__ C, long cz,
                        int K, int N,
                        const float* __restrict__ bias, int act)
{
  __shared__ float al[32*68];
  __shared__ float bl[32*68];
  const int mt = blockIdx.x*64, nt = blockIdx.y*64, zz = blockIdx.z;
  const int j = threadIdx.x;
  const float* Ap = A + (long)az*zz;
  const float* Bp = B + (long)bz*zz;
  const int tx = j&15, ty = j>>4;
  float acc[4][4];
  #pragma unroll
  for (int i=0;i<4;++i){acc[i][0]=0;acc[i][1]=0;acc[i][2]=0;acc[i][3]=0;}
  for (int k0=0;k0<K;k0+=32){
    #pragma unroll
    for (int half=0; half<2; ++half){
      int idx = j + half*256;
      int r = idx>>3, kk=(idx&7)*4;
      float4 v = *(const float4*)&Ap[(long)(mt+r)*K + k0+kk];
      al[(kk+0)*68+r]=v.x; al[(kk+1)*68+r]=v.y; al[(kk+2)*68+r]=v.z; al[(kk+3)*68+r]=v.w;
    }
    #pragma unroll
    for (int half=0; half<2; ++half){
      int idx = j + half*256;
      int r = idx>>4, cc=(idx&15)*4;
      *(float4*)&bl[r*68+cc] = *(const float4*)&Bp[(long)(k0+r)*N + nt+cc];
    }
    __syncthreads();
    #pragma unroll
    for (int kk=0;kk<32;++kk){
      float4 a = *(const float4*)&al[kk*68+ty*4];
      float4 b = *(const float4*)&bl[kk*68+tx*4];
      acc[0][0]+=a.x*b.x; acc[0][1]+=a.x*b.y; acc[0][2]+=a.x*b.z; acc[0][3]+=a.x*b.w;
      acc[1][0]+=a.y*b.x; acc[1][1]+=a.y*b.y; acc[1][2]+=a.y*b.z; acc[1][3]+=a.y*b.w;
      acc[2][0]+=a.z*b.x; acc[2][1]+=a.z*b.y; acc[2][2]+=a.z*b.z; acc[2][3]+=a.z*b.w;
      acc[3][0]+=a.w*b.x; acc[3][1]+=a.w*b.y; acc[3][2]+=a.w*b.z; acc[3][3]+=a.w*b.w;
    }
    __syncthreads();
  }
  #pragma unroll
  for (int i=0;i<4;++i){
    int row = mt+ty*4+i;
    #pragma unroll
    for (int m=0;m<4;++m){
      int col = nt+tx*4+m;
      float v = acc[i][m];
      if (bias) v += bias[col];
      if (act==1) v = fmaxf(v,0.f);
      else if (act==2) v = (v>0.f)? v : 0.1f*v;
      C[(long)cz*zz + (long)row*N + col] = v;
    }
  }
}

// ---------------- NT GEMM with scale: C = scale * A @ B^T ----------------
__launch_bounds__(256,1)
__global__ void gemm_nt_scaled(const float* __restrict__ A, const float* __restrict__ B,
                               float* __restrict__ C, int K, float scale)
{
  __shared__ float al[32*68];
  __shared__ float bl[32*68];
  const int mt = blockIdx.x*64, nt = blockIdx.y*64;
  const int j = threadIdx.x;
  const int tx = j&15, ty = j>>4;
  float acc[4][4];
  #pragma unroll
  for (int i=0;i<4;++i){acc[i][0]=0;acc[i][1]=0;acc[i][2]=0;acc[i][3]=0;}
  for (int k0=0;k0<K;k0+=32){
    #pragma unroll
    for (int half=0; half<2; ++half){
      int idx = j + half*256;
      int r = idx>>3, kk=(idx&7)*4;
      float4 v = *(const float4*)&A[(long)(mt+r)*K + k0+kk];
      al[(kk+0)*68+r]=v.x; al[(kk+1)*68+r]=v.y; al[(kk+2)*68+r]=v.z; al[(kk+3)*68+r]=v.w;
    }
    #pragma unroll
    for (int half=0; half<2; ++half){
      int idx = j + half*256;
      int r = idx>>3, kk=(idx&7)*4;
      float4 v = *(const float4*)&B[(long)(nt+r)*K + k0+kk];
      bl[(kk+0)*68+r]=v.x; bl[(kk+1)*68+r]=v.y; bl[(kk+2)*68+r]=v.z; bl[(kk+3)*68+r]=v.w;
    }
    __syncthreads();
    #pragma unroll
    for (int kk=0;kk<32;++kk){
      float4 a = *(const float4*)&al[kk*68+ty*4];
      float4 b = *(const float4*)&bl[kk*68+tx*4];
      acc[0][0]+=a.x*b.x; acc[0][1]+=a.x*b.y; acc[0][2]+=a.x*b.z; acc[0][3]+=a.x*b.w;
      acc[1][0]+=a.y*b.x; acc[1][1]+=a.y*b.y; acc[1][2]+=a.y*b.z; acc[1][3]+=a.y*b.w;
      acc[2][0]+=a.z*b.x; acc[2][1]+=a.z*b.y; acc[2][2]+=a.z*b.z; acc[2][3]+=a.z*b.w;
      acc[3][0]+=a.w*b.x; acc[3][1]+=a.w*b.y; acc[3][2]+=a.w*b.z; acc[3][3]+=a.w*b.w;
    }
    __syncthreads();
  }
  #pragma unroll
  for (int i=0;i<4;++i){
    #pragma unroll
    for (int m=0;m<4;++m){
      C[(long)(mt+ty*4+i)*S_ + nt+tx*4+m] = acc[i][m]*scale;
    }
  }
}

// ---------------- top-k + sparse softmax-gather ----------------
__launch_bounds__(256,1)
__global__ void topk_gather(const float* __restrict__ sim, const float* __restrict__ xs,
                            const int* __restrict__ Kp, float* __restrict__ dynpre)
{
  __shared__ float row[S_];
  __shared__ float work[S_];
  __shared__ float wred[4]; __shared__ int ired[4];
  __shared__ float selw[256]; __shared__ int seli[256];
  __shared__ int cnt; __shared__ float sh_kth, sh_max, sh_den;
  const int s = blockIdx.x, j = threadIdx.x;
  const float* rp = sim + (long)s*S_;
  for (int i=j;i<S_;i+=256){ float v=rp[i]; row[i]=v; work[i]=v; }
  if (j==0) cnt=0;
  __syncthreads();
  const int K = Kp[0];
  for (int it=0; it<K; ++it){
    float m=-3.0e38f; int mi=0;
    for (int i=j;i<S_;i+=256){ float v=work[i]; if (v>m){m=v;mi=i;} }
    #pragma unroll
    for (int o=32;o>=1;o>>=1){
      float om=__shfl_xor(m,o); int oi=__shfl_xor(mi,o);
      if (om>m){m=om;mi=oi;}
    }
    if ((j&63)==0){ wred[j>>6]=m; ired[j>>6]=mi; }
    __syncthreads();
    if (j==0){
      float bm=wred[0]; int bi=ired[0];
      #pragma unroll
      for (int w=1;w<4;++w) if (wred[w]>bm){bm=wred[w];bi=ired[w];}
      work[bi]=-3.0e38f;
      if (it==0) sh_max=bm;
      sh_kth=bm;
    }
    __syncthreads();
  }
  const float kth=sh_kth, rmax=sh_max;
  for (int i=j;i<S_;i+=256){
    float v=row[i];
    if (v>=kth){
      int p=atomicAdd(&cnt,1);
      if (p<256){ seli[p]=i; selw[p]=__expf(v-rmax); }
    }
  }
  __syncthreads();
  int c = cnt; if (c>256) c=256;
  {
    float p = (j<c)? selw[j] : 0.f;
    p = warp_sum64(p);
    if ((j&63)==0) wred[j>>6]=p;
    __syncthreads();
    if (j==0) sh_den = wred[0]+wred[1]+wred[2]+wred[3];
    __syncthreads();
  }
  float acc=0.f;
  for (int l=0;l<c;++l) acc += selw[l]*xs[(long)seli[l]*D_ + j];
  dynpre[(long)s*D_+j] = acc / sh_den;
}

// ---------------- hyper = sum_n ps[n] * reps[n] ----------------
__global__ void hyperwsum_kernel(const float* __restrict__ reps, const float* __restrict__ ps,
                                 float* __restrict__ hyper)
{
  long idx = (long)blockIdx.x*256+threadIdx.x;  // grid 2048
  hyper[idx] = ps[0]*reps[idx] + ps[1]*reps[(long)SD_+idx]
             + ps[2]*reps[2L*SD_+idx] + ps[3]*reps[3L*SD_+idx];
}

// ---------------- fusion ----------------
__global__ void fuse_kernel(const float* __restrict__ xs, const float* __restrict__ dyn,
                            const float* __restrict__ hyper, const float* __restrict__ beta,
                            float* __restrict__ fused)
{
  long idx = (long)blockIdx.x*256+threadIdx.x;  // grid 2048
  float b0=beta[0],b1=beta[1],b2=beta[2];
  float mx=fmaxf(b0,fmaxf(b1,b2));
  float e0=__expf(b0-mx),e1=__expf(b1-mx),e2=__expf(b2-mx);
  float inv=1.f/(e0+e1+e2);
  fused[idx] = e0*inv*xs[idx] + e1*inv*dyn[idx] + e2*inv*hyper[idx];
}

// ---------------- head: out = hh1 @ Wm2 + bm2 ----------------
__global__ void head_kernel(const float* __restrict__ hh1, const float* __restrict__ Wm2,
                            const float* __restrict__ bm2, float* __restrict__ out)
{
  int r = blockIdx.x*32 + (threadIdx.x>>3);   // grid 64
  int sub = threadIdx.x&7;
  const float* hp = hh1 + (long)r*D_;
  float acc=0.f;
  for (int c=sub;c<D_;c+=8) acc += hp[c]*Wm2[c];
  acc += __shfl_xor(acc,1); acc += __shfl_xor(acc,2); acc += __shfl_xor(acc,4);
  if (sub==0) out[r]=acc+bm2[0];
}

// ---------------- launch ----------------
extern "C" void kernel_launch(void* const* d_in, const int* in_sizes, int n_in,
                              void* d_out, int out_size, void* d_ws, size_t ws_size,
                              hipStream_t stream)
{
  (void)in_sizes;(void)n_in;(void)out_size;(void)ws_size;
  const float* x        =(const float*)d_in[0];
  const float* snapshot =(const float*)d_in[1];
  const float* ps       =(const float*)d_in[2];
  const float* beta     =(const float*)d_in[3];
  const float* Wemb=(const float*)d_in[4];  const float* bemb=(const float*)d_in[5];
  const float* Wq  =(const float*)d_in[6];  const float* bq  =(const float*)d_in[7];
  const float* Wk  =(const float*)d_in[8];  const float* bk  =(const float*)d_in[9];
  const float* Wv  =(const float*)d_in[10]; const float* bv  =(const float*)d_in[11];
  const float* Wo  =(const float*)d_in[12]; const float* bo  =(const float*)d_in[13];
  const float* ln1g=(const float*)d_in[14]; const float* ln1b=(const float*)d_in[15];
  const float* Wint=(const float*)d_in[16]; const float* bint=(const float*)d_in[17];
  const float* Wmix=(const float*)d_in[18]; const float* bmix=(const float*)d_in[19];
  const float* ln2g=(const float*)d_in[20]; const float* ln2b=(const float*)d_in[21];
  const float* Wt  =(const float*)d_in[22]; const float* bt  =(const float*)d_in[23];
  const float* vt  =(const float*)d_in[24];
  const float* Wh1 =(const float*)d_in[25]; const float* bh1 =(const float*)d_in[26];
  const float* filt1=(const float*)d_in[27];
  const float* Wh2 =(const float*)d_in[28]; const float* bh2 =(const float*)d_in[29];
  const float* filt2=(const float*)d_in[30];
  const float* Wa  =(const float*)d_in[31]; const float* Wb  =(const float*)d_in[32];
  const float* Wg  =(const float*)d_in[33]; const float* bg  =(const float*)d_in[34];
  const float* Wm1 =(const float*)d_in[35]; const float* bm1 =(const float*)d_in[36];
  const float* Wm2 =(const float*)d_in[37]; const float* bm2 =(const float*)d_in[38];
  const int* numedges=(const int*)d_in[39];
  float* out=(float*)d_out;

  // ---- workspace layout (floats). Peak ~46.6 MB. ----
  float* w = (float*)d_ws;
  float* Ppart = w;
  float* Hn    = w + 4194304;
  float* HnD   = Hn + 1048576;
  float* P     = HnD + 1048576;
  float* Dv    = P + 131072;
  float* De    = Dv + 8192;
  float* pe    = w;            // overlay (dead before first hg_phase1)
  float* repsb = w;            // overlay (after Ppart consumed)
  float* sim   = w;            // overlay (after repsb consumed)
  float* xs    = w + 6431232;
  float* hyper = xs + SD_;
  float* bufA  = hyper + SD_;          // NS*SD
  float* bufB  = bufA + 4*SD_;         // NS*SD
  float* p1    = bufA;
  float* q1    = bufA + SD_;
  float* dynpre= bufA + 2*SD_;
  float* dyn   = bufA + 3*SD_;
  float* fused = bufB;
  float* hh1   = bufB + SD_;
  short* pwh   = (short*)(w + PKBASE);
  short* pwl   = pwh + PKPLANE;

  hipMemsetAsync(De, 0, (size_t)NS_*E_*sizeof(float), stream);
  pe_kernel<<<64,256,0,stream>>>(pe);
  pack_weights<<<256,256,0,stream>>>(Wq,   pwh+OFFQ, pwl+OFFQ);
  pack_weights<<<256,256,0,stream>>>(Wk,   pwh+OFFK, pwl+OFFK);
  pack_weights<<<256,256,0,stream>>>(Wv,   pwh+OFFV, pwl+OFFV);
  pack_weights<<<256,256,0,stream>>>(Wo,   pwh+OFFO, pwl+OFFO);
  pack_weights<<<256,256,0,stream>>>(Wint, pwh+OFFI, pwl+OFFI);
  pack_weights<<<256,256,0,stream>>>(Wt,   pwh+OFFT, pwl+OFFT);
  pack_weights<<<512,256,0,stream>>>(Wmix, pwh+OFFM, pwl+OFFM);

  stageA_kernel<<<S_,256,0,stream>>>(x,pe,Wemb,bemb,bq,bk,bv,bo,
                                     ln1g,ln1b,bint,bmix,ln2g,ln2b,bt,vt,
                                     pwh,pwl,xs);
  hg_deg<<<dim3(32,NS_),256,0,stream>>>(snapshot,Dv,De);
  hg_scale<<<4096,256,0,stream>>>(snapshot,Dv,De,Hn,HnD);

  auto applyA=[&](const float* M, long mz,
                  const float* X1, long x1z, float c1,
                  const float* X2, long x2z, float c2, float c3,
                  const float* filt, int uf, float* outb){
    hg_phase1<<<dim3(KC_,NS_),256,0,stream>>>(Hn,M,mz,Ppart);
    hg_reduceP<<<dim3(8,NS_),256,0,stream>>>(Ppart,P);
    hg_phase2<<<dim3(32,4,NS_),256,0,stream>>>(HnD,P,X1,x1z,c1,X2,x2z,c2,c3,filt,uf,outb);
  };

  // ---- wavelet hypergraph conv, layer 1 ----
  applyA(xs,0,     xs,0,1.f,    nullptr,0,0.f,  -1.f,  nullptr,0, bufA);  // t1 = L z
  applyA(bufA,SD_, xs,0,1.f,    bufA,SD_,1.5f,  -0.5f, filt1,1,   bufB);  // y0
  applyA(bufB,SD_, bufB,SD_,1.f, nullptr,0,0.f, -1.f,  nullptr,0, bufA);  // t3
  applyA(bufA,SD_, bufB,SD_,1.f, bufA,SD_,-0.5f,-0.5f, nullptr,0, bufA);  // p
  gemm_nn<<<dim3(32,4,NS_),256,0,stream>>>(bufA,SD_, Wh1,0, bufB,SD_, 256,256, bh1, 2);

  // ---- layer 2 ----
  applyA(bufB,SD_, bufB,SD_,1.f, nullptr,0,0.f, -1.f,  nullptr,0, bufA);
  applyA(bufA,SD_, bufB,SD_,1.f, bufA,SD_,1.5f, -0.5f, filt2,1,   bufB);
  applyA(bufB,SD_, bufB,SD_,1.f, nullptr,0,0.f, -1.f,  nullptr,0, bufA);
  applyA(bufA,SD_, bufB,SD_,1.f, bufA,SD_,-0.5f,-0.5f, nullptr,0, bufA);
  gemm_nn<<<dim3(32,4,NS_),256,0,stream>>>(bufA,SD_, Wh2,0, repsb,SD_, 256,256, bh2, 0);
  hyperwsum_kernel<<<2048,256,0,stream>>>(repsb,ps,hyper);

  // ---- dynamic graph ----
  gemm_nn<<<dim3(32,4,1),256,0,stream>>>(xs,0, Wa,0, p1,0, 256,256, nullptr, 0);
  gemm_nn<<<dim3(32,4,1),256,0,stream>>>(xs,0, Wb,0, q1,0, 256,256, nullptr, 0);
  gemm_nt_scaled<<<dim3(32,32),256,0,stream>>>(p1,q1,sim,256,0.0625f);
  topk_gather<<<S_,256,0,stream>>>(sim,xs,numedges,dynpre);
  gemm_nn<<<dim3(32,4,1),256,0,stream>>>(dynpre,0, Wg,0, dyn,0, 256,256, bg, 1);

  // ---- fusion + head ----
  fuse_kernel<<<2048,256,0,stream>>>(xs,dyn,hyper,beta,fused);
  gemm_nn<<<dim3(32,4,1),256,0,stream>>>(fused,0, Wm1,0, hh1,0, 256,256, bm1, 1);
  head_kernel<<<64,256,0,stream>>>(hh1,Wm2,bm2,out);
}

// Round 5
// 1459.226 us; speedup vs baseline: 3.3082x; 1.2762x over previous
//
#include <hip/hip_runtime.h>
#include <math.h>

#define S_ 2048
#define T_ 64
#define F_ 16
#define D_ 256
#define NS_ 4
#define E_ 128
#define H_ 8
#define KC_ 32
#define SD_ (S_*D_)
#define HS 260   // hbuf row stride (pad +4: 2-way LDS conflict = free)

// packed-weight combined buffer (shorts), round-contiguous
#define PK_ATT 0         // 4hp x 8kt x 12288 shorts (Qh,Ql,Kh,Kl,Vh,Vl x 2048)
#define PK_WO  393216    // 8 kt-tiles x 16384 (hi 8192 | lo 8192)
#define PK_WI  524288
#define PK_WT  655360
#define PK_WM  786432    // 16 kt-tiles
#define PKBASE 11674112  // float offset in ws where pkc starts (2MB)

typedef __attribute__((ext_vector_type(8))) short bf16x8;
typedef __attribute__((ext_vector_type(4))) float f32x4;

// ---------------- helpers ----------------
__device__ __forceinline__ float warp_sum64(float v){
  #pragma unroll
  for (int o=32;o>=1;o>>=1) v += __shfl_xor(v,o);
  return v;
}
__device__ __forceinline__ float warp_max64(float v){
  #pragma unroll
  for (int o=32;o>=1;o>>=1) v = fmaxf(v,__shfl_xor(v,o));
  return v;
}
__device__ __forceinline__ float softplus_f(float v){
  return fmaxf(v,0.f) + log1pf(__expf(-fabsf(v)));
}
__device__ __forceinline__ float tanh_f(float v){
  float t = __expf(-2.f*fabsf(v));
  float r = (1.f-t)/(1.f+t);
  return copysignf(r, v);
}
// split fp32 into bf16 hi + bf16 lo (RNE); a ~= hi + lo with ~2^-18 residual
__device__ __forceinline__ void splitf(float f, short& h, short& l){
  unsigned u = __float_as_uint(f);
  unsigned hb = (u + 0x7FFFu + ((u>>16)&1u)) >> 16;
  float fl = f - __uint_as_float(hb<<16);
  unsigned v = __float_as_uint(fl);
  unsigned lb = (v + 0x7FFFu + ((v>>16)&1u)) >> 16;
  h = (short)hb; l = (short)lb;
}
// fp32-emulating 3-MFMA accumulate (lowest-magnitude terms first)
__device__ __forceinline__ f32x4 mfma3(bf16x8 ah, bf16x8 al, bf16x8 bh, bf16x8 bl, f32x4 c){
  c = __builtin_amdgcn_mfma_f32_16x16x32_bf16(al, bh, c, 0,0,0);
  c = __builtin_amdgcn_mfma_f32_16x16x32_bf16(ah, bl, c, 0,0,0);
  c = __builtin_amdgcn_mfma_f32_16x16x32_bf16(ah, bh, c, 0,0,0);
  return c;
}
// A-fragment from fp32 LDS: A[m=lane&15][k=(lane>>4)*8+j]
__device__ __forceinline__ void afrag_f32(const float* base, int stride, int rbase, int ks, int lane, bf16x8& hi, bf16x8& lo){
  const float* p = base + (rbase + (lane&15))*stride + ks + ((lane>>4)<<3);
  #pragma unroll
  for (int jj=0;jj<8;++jj){ short h,l; splitf(p[jj],h,l); hi[jj]=h; lo[jj]=l; }
}
// B-fragment from packed (hi|lo<<16) uint32 LDS tiles
__device__ __forceinline__ void bfrag_pk(const unsigned* pk, int tile, int lane, bf16x8& hi, bf16x8& lo){
  const unsigned* p = pk + (((tile<<6) + lane)<<3);
  #pragma unroll
  for (int jj=0;jj<8;++jj){ unsigned u=p[jj]; hi[jj]=(short)(u & 0xffffu); lo[jj]=(short)(u>>16); }
}

// ---------------- weight packing (round-contiguous combined layout) ----------------
// QKV: per (hp,kt) round of 12288 shorts: [Qhi|Qlo|Khi|Klo|Vhi|Vlo] x (4nt x 512)
__global__ void pack_qkv(const float* __restrict__ W, short* __restrict__ dst, int vplane){
  int i = blockIdx.x*256 + threadIdx.x;   // 65536
  int jj=i&7, n=(i>>3)&15, q=(i>>7)&3, ntg=(i>>9)&15, kt=i>>13;
  float f = W[(kt*32 + q*8 + jj)*256 + (ntg*16+n)];
  short h,l; splitf(f,h,l);
  int hp = ntg>>2, ntl = ntg&3;
  int base = ((hp*8+kt)*6 + vplane*2)*2048;
  int local = ntl*512 + (q*16+n)*8 + jj;
  dst[base+local] = h;
  dst[base+2048+local] = l;
}
// post: per kt-tile 16384 shorts: [hi 16nt x 512 | lo 16nt x 512]
__global__ void pack_post(const float* __restrict__ W, short* __restrict__ dst){
  int i = blockIdx.x*256 + threadIdx.x;
  int jj=i&7, n=(i>>3)&15, q=(i>>7)&3, ntg=(i>>9)&15, kt=i>>13;
  float f = W[(kt*32 + q*8 + jj)*256 + (ntg*16+n)];
  short h,l; splitf(f,h,l);
  int dl = kt*16384 + ntg*512 + (q*16+n)*8 + jj;
  dst[dl] = h;
  dst[dl+8192] = l;
}

// ---------------- positional encoding ----------------
__global__ void pe_kernel(float* __restrict__ pe){
  int i = blockIdx.x*256 + threadIdx.x;       // grid 64 -> 16384
  int t = i >> 8, d = i & 255;
  int ii = d >> 1;
  float w = __expf(-(float)ii * (logf(10000.f)/128.f));
  float ang = (float)t * w;
  pe[i] = (d & 1) ? cosf(ang) : sinf(ang);
}

// ---------------- stage A: 512-thread (2 waves/SIMD) MFMA pipeline ----------------
// LDS: hbuf 66560 + smem 85504 = 152064 B -> 1 block/CU, 8 waves
__launch_bounds__(512,1)
__global__ void stageA_kernel(
    const float* __restrict__ x, const float* __restrict__ pe,
    const float* __restrict__ Wemb, const float* __restrict__ bemb,
    const float* __restrict__ bq, const float* __restrict__ bk, const float* __restrict__ bv,
    const float* __restrict__ bo,
    const float* __restrict__ ln1g, const float* __restrict__ ln1b,
    const float* __restrict__ bint,
    const float* __restrict__ bmix,
    const float* __restrict__ ln2g, const float* __restrict__ ln2b,
    const float* __restrict__ bt,
    const float* __restrict__ vt,
    const short* __restrict__ pkc,
    float* __restrict__ xs)
{
  __shared__ float hbuf[T_][HS];                       // 66560
  __shared__ __attribute__((aligned(16))) char smem[85504];

  short*    wst   = (short*)smem;                      // 32KB staging
  unsigned* k2f2  = (unsigned*)smem;                   // overlay: 2 heads x 2048 u32
  unsigned* v2f2  = (unsigned*)(smem + 16384);         // overlay: 16KB
  float*    qb2   = (float*)(smem + 32768);            // [64][68] q / o_h
  float*    scb2  = (float*)(smem + 50176);            // 2 x [64][68] probs (per head parity)
  float*    smallb= (float*)(smem + 84992);            // 128 floats

  const int j  = threadIdx.x;
  const int s  = blockIdx.x;
  const int w  = j >> 6;            // wave 0..7
  const int lane = j & 63;
  const int m_ = lane & 15, qd = lane >> 4;
  const int rg2 = w >> 1, par = w & 1;
  const int rbase = rg2*16;         // MFMA row-tile base (shared by parity pair)
  const int rv = w*8;               // vector-op rows (8 per wave)
  const int c0 = lane;

  // ---- stage x[s] ----
  {
    float* xb = (float*)smem;
    const float* xp = x + (long)s*T_*F_;
    for (int i=j; i<T_*F_; i+=512) xb[i] = xp[i];
  }
  __syncthreads();

  // ---- embedding + PE (rows rv..rv+8) ----
  {
    const float* xb = (const float*)smem;
    float acc[8][4];
    #pragma unroll
    for (int r=0;r<8;++r){acc[r][0]=0;acc[r][1]=0;acc[r][2]=0;acc[r][3]=0;}
    #pragma unroll
    for (int k=0;k<F_;++k){
      float w0=Wemb[k*D_+c0], w1=Wemb[k*D_+c0+64], w2=Wemb[k*D_+c0+128], w3=Wemb[k*D_+c0+192];
      #pragma unroll
      for (int r=0;r<8;++r){
        float hv = xb[(rv+r)*F_+k];
        acc[r][0]+=hv*w0; acc[r][1]+=hv*w1; acc[r][2]+=hv*w2; acc[r][3]+=hv*w3;
      }
    }
    float b0=bemb[c0],b1=bemb[c0+64],b2=bemb[c0+128],b3=bemb[c0+192];
    #pragma unroll
    for (int r=0;r<8;++r){
      int t = rv+r;
      hbuf[t][c0]     = acc[r][0]+b0+pe[t*D_+c0];
      hbuf[t][c0+64]  = acc[r][1]+b1+pe[t*D_+c0+64];
      hbuf[t][c0+128] = acc[r][2]+b2+pe[t*D_+c0+128];
      hbuf[t][c0+192] = acc[r][3]+b3+pe[t*D_+c0+192];
    }
  }
  __syncthreads();

  // ---- hoist QKV A-fragments (rows rbase, duplicated across parity pair) ----
  bf16x8 AH[8], AL[8];
  #pragma unroll
  for (int kt=0;kt<8;++kt) afrag_f32(&hbuf[0][0], HS, rbase, kt*32, lane, AH[kt], AL[kt]);

  const float rs = 0.17677669529663687f;  // 1/sqrt(32)
  f32x4 co[8];
  #pragma unroll
  for (int t=0;t<8;++t) co[t] = (f32x4){0.f,0.f,0.f,0.f};

  // ---- attention: head pairs, head = parity ----
  for (int hp=0; hp<4; ++hp){
    f32x4 qa[2],ka[2],va[2];
    #pragma unroll
    for (int t=0;t<2;++t){
      qa[t]=(f32x4){0.f,0.f,0.f,0.f};
      ka[t]=(f32x4){0.f,0.f,0.f,0.f};
      va[t]=(f32x4){0.f,0.f,0.f,0.f};
    }
    bf16x8 pre[3];
    {
      const short* b0 = pkc + PK_ATT + (hp*8)*12288;
      #pragma unroll
      for (int r=0;r<3;++r) pre[r] = *(const bf16x8*)(b0 + (j+r*512)*8);
    }
    for (int kt=0; kt<8; ++kt){
      __syncthreads();                                  // prior wst consumers done
      #pragma unroll
      for (int r=0;r<3;++r) *(bf16x8*)(wst + (j+r*512)*8) = pre[r];
      __syncthreads();                                  // tile ready
      if (kt<7){
        const short* nb = pkc + PK_ATT + (hp*8+kt+1)*12288;
        #pragma unroll
        for (int r=0;r<3;++r) pre[r] = *(const bf16x8*)(nb + (j+r*512)*8);
      }
      bf16x8 ah = AH[kt], al = AL[kt];
      #pragma unroll
      for (int t=0;t<2;++t){
        int ntl = par*2+t;
        bf16x8 bh,bl;
        bh = *(bf16x8*)(wst +         ntl*512 + lane*8);
        bl = *(bf16x8*)(wst + 2048  + ntl*512 + lane*8);
        qa[t]=mfma3(ah,al,bh,bl,qa[t]);
        bh = *(bf16x8*)(wst + 4096  + ntl*512 + lane*8);
        bl = *(bf16x8*)(wst + 6144  + ntl*512 + lane*8);
        ka[t]=mfma3(ah,al,bh,bl,ka[t]);
        bh = *(bf16x8*)(wst + 8192  + ntl*512 + lane*8);
        bl = *(bf16x8*)(wst + 10240 + ntl*512 + lane*8);
        va[t]=mfma3(ah,al,bh,bl,va[t]);
      }
    }
    __syncthreads();   // QKV MFMAs done; epilogue overwrites wst region (k2f2/v2f2)
    // epilogue: q->qb2 (scaled), k/v -> packed B-frag LDS
    #pragma unroll
    for (int t=0;t<2;++t){
      int ntg = par*2+t;
      #pragma unroll
      for (int r=0;r<4;++r){
        int trow = rbase + qd*4 + r;
        int pcp = ntg*16 + m_;
        int head = pcp >> 5;
        int cp = pcp & 31;
        int col = hp*64 + pcp;
        qb2[trow*68 + pcp] = (qa[t][r] + bq[col]) * rs;
        short hS,lS;
        float kv2 = ka[t][r] + bk[col];
        splitf(kv2,hS,lS);
        k2f2[head*2048 + (((trow>>4)*4 + (cp>>3))*16 + (trow&15))*8 + (cp&7)]
            = (unsigned)(unsigned short)hS | ((unsigned)(unsigned short)lS<<16);
        float vv2 = va[t][r] + bv[col];
        splitf(vv2,hS,lS);
        v2f2[head*2048 + ((((trow>>5)*2 + (cp>>4))*4 + ((trow>>3)&3))*16 + (cp&15))*8 + (trow&7)]
            = (unsigned)(unsigned short)hS | ((unsigned)(unsigned short)lS<<16);
      }
    }
    __syncthreads();   // k2f2/v2f2 visible to all waves
    // ---- scores + softmax (head = par, rows rbase, in-wave) ----
    float* scb = scb2 + par*4352;
    {
      bf16x8 ah,al;
      afrag_f32(qb2, 68, rbase, par*32, lane, ah, al);
      f32x4 sc4[4];
      #pragma unroll
      for (int nt=0;nt<4;++nt){
        bf16x8 bh,bl; bfrag_pk(k2f2 + par*2048, nt, lane, bh, bl);
        sc4[nt] = mfma3(ah,al,bh,bl,(f32x4){0.f,0.f,0.f,0.f});
      }
      #pragma unroll
      for (int r=0;r<4;++r){
        float mx = fmaxf(fmaxf(sc4[0][r],sc4[1][r]),fmaxf(sc4[2][r],sc4[3][r]));
        #pragma unroll
        for (int o=8;o>=1;o>>=1) mx = fmaxf(mx, __shfl_xor(mx,o));
        float es = 0.f;
        #pragma unroll
        for (int nt=0;nt<4;++nt){ float e=__expf(sc4[nt][r]-mx); sc4[nt][r]=e; es+=e; }
        #pragma unroll
        for (int o=8;o>=1;o>>=1) es += __shfl_xor(es,o);
        float inv = 1.f/es;
        int trow = rbase + qd*4 + r;
        #pragma unroll
        for (int nt=0;nt<4;++nt) scb[trow*68 + nt*16 + m_] = sc4[nt][r]*inv;
      }
    }
    // ---- o = P @ V (head = par) ----
    {
      f32x4 oa[2];
      oa[0]=(f32x4){0.f,0.f,0.f,0.f}; oa[1]=(f32x4){0.f,0.f,0.f,0.f};
      #pragma unroll
      for (int kt=0;kt<2;++kt){
        bf16x8 ah2,al2; afrag_f32(scb, 68, rbase, kt*32, lane, ah2, al2);
        #pragma unroll
        for (int nt=0;nt<2;++nt){
          bf16x8 bh,bl; bfrag_pk(v2f2 + par*2048, kt*2+nt, lane, bh, bl);
          oa[nt]=mfma3(ah2,al2,bh,bl,oa[nt]);
        }
      }
      #pragma unroll
      for (int nt=0;nt<2;++nt){
        #pragma unroll
        for (int r=0;r<4;++r)
          qb2[(rbase+qd*4+r)*68 + par*32 + nt*16 + m_] = oa[nt][r];
      }
    }
    // ---- Wo accumulate (nt parity split) ----
    for (int ks=0; ks<2; ++ks){
      bf16x8 preo[4];
      {
        const short* wob = pkc + PK_WO + (hp*2+ks)*16384;
        #pragma unroll
        for (int r=0;r<4;++r) preo[r] = *(const bf16x8*)(wob + (j+r*512)*8);
      }
      __syncthreads();   // PV writes done; prior wst consumers done
      #pragma unroll
      for (int r=0;r<4;++r) *(bf16x8*)(wst + (j+r*512)*8) = preo[r];
      __syncthreads();
      bf16x8 ah,al; afrag_f32(qb2, 68, rbase, ks*32, lane, ah, al);
      #pragma unroll
      for (int t=0;t<8;++t){
        int ntg = 2*t+par;
        bf16x8 bh = *(bf16x8*)(wst +        ntg*512 + lane*8);
        bf16x8 bl = *(bf16x8*)(wst + 8192 + ntg*512 + lane*8);
        co[t]=mfma3(ah,al,bh,bl,co[t]);
      }
    }
  }

  // ---- residual + bo ----
  #pragma unroll
  for (int t=0;t<8;++t){
    int cc = (2*t+par)*16+m_;
    float bov = bo[cc];
    #pragma unroll
    for (int r=0;r<4;++r)
      hbuf[rbase+qd*4+r][cc] += co[t][r] + bov;
  }
  __syncthreads();

  // ---- LN1 (rows rv..rv+8) ----
  {
    float g0=ln1g[c0],g1=ln1g[c0+64],g2=ln1g[c0+128],g3=ln1g[c0+192];
    float bb0=ln1b[c0],bb1=ln1b[c0+64],bb2=ln1b[c0+128],bb3=ln1b[c0+192];
    for (int rr=0;rr<8;++rr){
      int t=rv+rr;
      float v0=hbuf[t][c0],v1=hbuf[t][c0+64],v2=hbuf[t][c0+128],v3=hbuf[t][c0+192];
      float sm=warp_sum64(v0+v1+v2+v3);
      float sq=warp_sum64(v0*v0+v1*v1+v2*v2+v3*v3);
      float mean=sm*(1.f/256.f);
      float inv=rsqrtf(fmaxf(sq*(1.f/256.f)-mean*mean,0.f)+1e-5f);
      hbuf[t][c0]    =(v0-mean)*inv*g0+bb0;
      hbuf[t][c0+64] =(v1-mean)*inv*g1+bb1;
      hbuf[t][c0+128]=(v2-mean)*inv*g2+bb2;
      hbuf[t][c0+192]=(v3-mean)*inv*g3+bb3;
    }
  }
  __syncthreads();

  // ---- Wmix part1 (A = h, kt 0..7) ----
  f32x4 az[8];
  #pragma unroll
  for (int t=0;t<8;++t) az[t]=(f32x4){0.f,0.f,0.f,0.f};
  {
    bf16x8 prew[4];
    #pragma unroll
    for (int r=0;r<4;++r) prew[r] = *(const bf16x8*)(pkc + PK_WM + (j+r*512)*8);
    for (int kt=0; kt<8; ++kt){
      __syncthreads();
      #pragma unroll
      for (int r=0;r<4;++r) *(bf16x8*)(wst + (j+r*512)*8) = prew[r];
      __syncthreads();
      if (kt<7){
        const short* nb = pkc + PK_WM + (kt+1)*16384;
        #pragma unroll
        for (int r=0;r<4;++r) prew[r] = *(const bf16x8*)(nb + (j+r*512)*8);
      }
      bf16x8 ah,al; afrag_f32(&hbuf[0][0], HS, rbase, kt*32, lane, ah, al);
      #pragma unroll
      for (int t=0;t<8;++t){
        int ntg = 2*t+par;
        bf16x8 bh = *(bf16x8*)(wst +        ntg*512 + lane*8);
        bf16x8 bl = *(bf16x8*)(wst + 8192 + ntg*512 + lane*8);
        az[t]=mfma3(ah,al,bh,bl,az[t]);
      }
    }
  }

  // ---- Wint: intensity ----
  {
    f32x4 ai[8];
    #pragma unroll
    for (int t=0;t<8;++t) ai[t]=(f32x4){0.f,0.f,0.f,0.f};
    bf16x8 prew[4];
    #pragma unroll
    for (int r=0;r<4;++r) prew[r] = *(const bf16x8*)(pkc + PK_WI + (j+r*512)*8);
    for (int kt=0; kt<8; ++kt){
      __syncthreads();
      #pragma unroll
      for (int r=0;r<4;++r) *(bf16x8*)(wst + (j+r*512)*8) = prew[r];
      __syncthreads();
      if (kt<7){
        const short* nb = pkc + PK_WI + (kt+1)*16384;
        #pragma unroll
        for (int r=0;r<4;++r) prew[r] = *(const bf16x8*)(nb + (j+r*512)*8);
      }
      bf16x8 ah,al; afrag_f32(&hbuf[0][0], HS, rbase, kt*32, lane, ah, al);
      #pragma unroll
      for (int t=0;t<8;++t){
        int ntg = 2*t+par;
        bf16x8 bh = *(bf16x8*)(wst +        ntg*512 + lane*8);
        bf16x8 bl = *(bf16x8*)(wst + 8192 + ntg*512 + lane*8);
        ai[t]=mfma3(ah,al,bh,bl,ai[t]);
      }
    }
    __syncthreads();   // all Wint MFMAs (h readers) done before overwrite
    #pragma unroll
    for (int t=0;t<8;++t){
      int cc = (2*t+par)*16+m_;
      float bb = bint[cc];
      #pragma unroll
      for (int r=0;r<4;++r)
        hbuf[rbase+qd*4+r][cc] = softplus_f(ai[t][r]+bb);
    }
  }

  // ---- Wmix part2 (A = intensity, kt 8..15) ----
  {
    bf16x8 prew[4];
    #pragma unroll
    for (int r=0;r<4;++r) prew[r] = *(const bf16x8*)(pkc + PK_WM + 8*16384 + (j+r*512)*8);
    for (int kt=0; kt<8; ++kt){
      __syncthreads();   // (round0: intensity writes visible)
      #pragma unroll
      for (int r=0;r<4;++r) *(bf16x8*)(wst + (j+r*512)*8) = prew[r];
      __syncthreads();
      if (kt<7){
        const short* nb = pkc + PK_WM + (9+kt)*16384;
        #pragma unroll
        for (int r=0;r<4;++r) prew[r] = *(const bf16x8*)(nb + (j+r*512)*8);
      }
      bf16x8 ah,al; afrag_f32(&hbuf[0][0], HS, rbase, kt*32, lane, ah, al);
      #pragma unroll
      for (int t=0;t<8;++t){
        int ntg = 2*t+par;
        bf16x8 bh = *(bf16x8*)(wst +        ntg*512 + lane*8);
        bf16x8 bl = *(bf16x8*)(wst + 8192 + ntg*512 + lane*8);
        az[t]=mfma3(ah,al,bh,bl,az[t]);
      }
    }
  }
  __syncthreads();   // all Wmix p2 MFMAs (intensity readers) done
  // z = relu(az+bmix) -> hbuf
  #pragma unroll
  for (int t=0;t<8;++t){
    int cc = (2*t+par)*16+m_;
    float bb = bmix[cc];
    #pragma unroll
    for (int r=0;r<4;++r)
      hbuf[rbase+qd*4+r][cc] = fmaxf(az[t][r]+bb,0.f);
  }
  __syncthreads();

  // ---- LN2 (rows rv..rv+8) ----
  {
    float g0=ln2g[c0],g1=ln2g[c0+64],g2=ln2g[c0+128],g3=ln2g[c0+192];
    float bb0=ln2b[c0],bb1=ln2b[c0+64],bb2=ln2b[c0+128],bb3=ln2b[c0+192];
    for (int rr=0;rr<8;++rr){
      int t=rv+rr;
      float v0=hbuf[t][c0],v1=hbuf[t][c0+64],v2=hbuf[t][c0+128],v3=hbuf[t][c0+192];
      float sm=warp_sum64(v0+v1+v2+v3);
      float sq=warp_sum64(v0*v0+v1*v1+v2*v2+v3*v3);
      float mean=sm*(1.f/256.f);
      float inv=rsqrtf(fmaxf(sq*(1.f/256.f)-mean*mean,0.f)+1e-5f);
      hbuf[t][c0]    =(v0-mean)*inv*g0+bb0;
      hbuf[t][c0+64] =(v1-mean)*inv*g1+bb1;
      hbuf[t][c0+128]=(v2-mean)*inv*g2+bb2;
      hbuf[t][c0+192]=(v3-mean)*inv*g3+bb3;
    }
  }

  // ---- Wt: u = tanh(h@Wt+bt), pooled in-register ----
  {
    f32x4 at4[8];
    #pragma unroll
    for (int t=0;t<8;++t) at4[t]=(f32x4){0.f,0.f,0.f,0.f};
    bf16x8 prew[4];
    #pragma unroll
    for (int r=0;r<4;++r) prew[r] = *(const bf16x8*)(pkc + PK_WT + (j+r*512)*8);
    for (int kt=0; kt<8; ++kt){
      __syncthreads();   // (round0: LN2 writes visible)
      #pragma unroll
      for (int r=0;r<4;++r) *(bf16x8*)(wst + (j+r*512)*8) = prew[r];
      __syncthreads();
      if (kt<7){
        const short* nb = pkc + PK_WT + (kt+1)*16384;
        #pragma unroll
        for (int r=0;r<4;++r) prew[r] = *(const bf16x8*)(nb + (j+r*512)*8);
      }
      bf16x8 ah,al; afrag_f32(&hbuf[0][0], HS, rbase, kt*32, lane, ah, al);
      #pragma unroll
      for (int t=0;t<8;++t){
        int ntg = 2*t+par;
        bf16x8 bh = *(bf16x8*)(wst +        ntg*512 + lane*8);
        bf16x8 bl = *(bf16x8*)(wst + 8192 + ntg*512 + lane*8);
        at4[t]=mfma3(ah,al,bh,bl,at4[t]);
      }
    }
    float pr[4] = {0.f,0.f,0.f,0.f};
    #pragma unroll
    for (int t=0;t<8;++t){
      int cc = (2*t+par)*16+m_;
      float btc = bt[cc], vtc = vt[cc];
      #pragma unroll
      for (int r=0;r<4;++r) pr[r] += tanh_f(at4[t][r]+btc)*vtc;
    }
    #pragma unroll
    for (int r=0;r<4;++r){
      float p = pr[r];
      p += __shfl_xor(p,1); p += __shfl_xor(p,2);
      p += __shfl_xor(p,4); p += __shfl_xor(p,8);
      if (m_==0) smallb[par*64 + rbase + qd*4 + r] = p;
    }
  }
  __syncthreads();
  if (j < 64){
    float v = smallb[j] + smallb[64+j];
    float m = warp_max64(v);
    float e = __expf(v-m);
    float ssum = warp_sum64(e);
    smallb[64+j] = e/ssum;
  }
  __syncthreads();
  if (j < 256){
    float acc=0.f;
    #pragma unroll 8
    for (int t=0;t<T_;++t) acc += smallb[64+t]*hbuf[t][j];
    xs[(long)s*D_+j] = acc;
  }
}

// ---------------- hypergraph prep ----------------
__global__ void hg_deg(const float* __restrict__ Hinc, float* __restrict__ Dv, float* __restrict__ De){
  const int n = blockIdx.y, s0 = blockIdx.x*64;   // grid (32, NS)
  const float* Hp = Hinc + (long)n*S_*E_;
  const int j = threadIdx.x;
  {
    int r = j>>2, q = j&3;
    const float* rp = Hp + (long)(s0+r)*E_ + q*32;
    float sm=0;
    #pragma unroll
    for (int e=0;e<32;++e) sm += rp[e];
    sm += __shfl_xor(sm,1); sm += __shfl_xor(sm,2);
    if (q==0) Dv[n*S_+s0+r]=sm+1e-6f;
  }
  if (j < E_){
    float cs=0;
    for (int ss=0;ss<64;++ss) cs += Hp[(long)(s0+ss)*E_+j];
    atomicAdd(&De[n*E_+j], cs);   // integer-valued fp32 adds: exact, deterministic
  }
}

__global__ void hg_scale(const float* __restrict__ Hinc, const float* __restrict__ Dv,
                         const float* __restrict__ De, float* __restrict__ Hn, float* __restrict__ HnD){
  long i = (long)blockIdx.x*256+threadIdx.x;   // grid 4096
  int n = (int)(i >> 18);
  int rem = (int)(i & 262143);
  int srow = rem >> 7;
  int e = rem & 127;
  float h = Hinc[i];
  float hn = h * rsqrtf(Dv[n*S_+srow]);
  Hn[i] = hn;
  HnD[i] = hn / (De[n*E_+e]+1e-6f);
}

// P-partial: Ppart[n][kc] = Hn_chunk^T @ M_chunk (chunk = 64 rows of S; D split in halves)
__launch_bounds__(256,1)
__global__ void hg_phase1(const float* __restrict__ Hn, const float* __restrict__ M,
                          long mz, float* __restrict__ Ppart)
{
  __shared__ float hl[64*E_];
  __shared__ float ml[64*128];
  const int kc = blockIdx.x, dh = blockIdx.y, n = blockIdx.z;  // grid (KC,2,NS)
  const int j = threadIdx.x;
  const float* Hp = Hn + ((long)n*S_ + (long)kc*64)*E_;
  const float* Mp = M + (long)n*mz + (long)kc*64*D_ + dh*128;
  for (int i=j*4; i<64*E_; i+=1024) *(float4*)&hl[i] = *(const float4*)&Hp[i];
  for (int i=j*4; i<64*128; i+=1024){
    int row = i>>7, cc = i&127;
    *(float4*)&ml[i] = *(const float4*)&Mp[(long)row*D_ + cc];
  }
  __syncthreads();
  const int eg = j & 15, dg = j >> 4;
  float acc[8][8];
  #pragma unroll
  for (int e=0;e<8;++e){
    #pragma unroll
    for (int d=0;d<8;++d) acc[e][d]=0.f;
  }
  for (int ss=0; ss<64; ++ss){
    float hv[8], mv[8];
    *(float4*)&hv[0] = *(const float4*)&hl[ss*E_+eg*8];
    *(float4*)&hv[4] = *(const float4*)&hl[ss*E_+eg*8+4];
    *(float4*)&mv[0] = *(const float4*)&ml[ss*128+dg*8];
    *(float4*)&mv[4] = *(const float4*)&ml[ss*128+dg*8+4];
    #pragma unroll
    for (int e=0;e<8;++e){
      #pragma unroll
      for (int d=0;d<8;++d) acc[e][d] += hv[e]*mv[d];
    }
  }
  float* Pp = Ppart + (long)(n*KC_+kc)*E_*D_ + dh*128;
  #pragma unroll
  for (int e=0;e<8;++e){
    int erow = eg*8+e;
    #pragma unroll
    for (int d4=0;d4<8;d4+=4){
      float4 v = make_float4(acc[e][d4],acc[e][d4+1],acc[e][d4+2],acc[e][d4+3]);
      *(float4*)&Pp[(long)erow*D_ + dg*8 + d4] = v;
    }
  }
}

__global__ void hg_reduceP(const float* __restrict__ Ppart, float* __restrict__ P){
  const int n = blockIdx.y;
  int base = blockIdx.x*1024;    // grid (32, NS)
  for (int i = base + threadIdx.x; i < base+1024; i += 256){
    const float* pp = Ppart + (long)n*KC_*E_*D_ + i;
    float a = 0;
    #pragma unroll
    for (int kc=0;kc<KC_;++kc) a += pp[(long)kc*E_*D_];
    P[(long)n*E_*D_ + i] = a;
  }
}

// out = filt * (c1*X1 + c2*X2 + c3*(HnD @ P)); in-place safe vs X1/X2
__launch_bounds__(256,1)
__global__ void hg_phase2(const float* __restrict__ HnD, const float* __restrict__ P,
                          const float* __restrict__ X1, long x1z, float c1,
                          const float* __restrict__ X2, long x2z, float c2,
                          float c3, const float* __restrict__ filt, int usefilt,
                          float* __restrict__ out)
{
  __shared__ float al[E_*68];
  __shared__ float pl[E_*68];
  const int st = blockIdx.x*64, dt = blockIdx.y*64, n = blockIdx.z;
  const int j = threadIdx.x;
  {
    const int r = j >> 2, k0 = (j&3)*32;
    const float* hp = HnD + ((long)n*S_ + st + r)*E_ + k0;
    #pragma unroll
    for (int kk=0; kk<32; kk+=4){
      float4 v = *(const float4*)&hp[kk];
      al[(k0+kk+0)*68+r]=v.x;
      al[(k0+kk+1)*68+r]=v.y;
      al[(k0+kk+2)*68+r]=v.z;
      al[(k0+kk+3)*68+r]=v.w;
    }
  }
  for (int idx=j; idx<E_*16; idx+=256){
    int k = idx>>4, dsub = (idx&15)*4;
    *(float4*)&pl[k*68+dsub] = *(const float4*)&P[((long)n*E_+k)*D_ + dt + dsub];
  }
  __syncthreads();
  const int tx = j&15, ty = j>>4;
  float acc[4][4];
  #pragma unroll
  for (int i=0;i<4;++i){acc[i][0]=0;acc[i][1]=0;acc[i][2]=0;acc[i][3]=0;}
  for (int k=0;k<E_;++k){
    float4 a = *(const float4*)&al[k*68+ty*4];
    float4 b = *(const float4*)&pl[k*68+tx*4];
    acc[0][0]+=a.x*b.x; acc[0][1]+=a.x*b.y; acc[0][2]+=a.x*b.z; acc[0][3]+=a.x*b.w;
    acc[1][0]+=a.y*b.x; acc[1][1]+=a.y*b.y; acc[1][2]+=a.y*b.z; acc[1][3]+=a.y*b.w;
    acc[2][0]+=a.z*b.x; acc[2][1]+=a.z*b.y; acc[2][2]+=a.z*b.z; acc[2][3]+=a.z*b.w;
    acc[3][0]+=a.w*b.x; acc[3][1]+=a.w*b.y; acc[3][2]+=a.w*b.z; acc[3][3]+=a.w*b.w;
  }
  #pragma unroll
  for (int i=0;i<4;++i){
    int srow = st + ty*4 + i;
    float f = usefilt ? filt[srow] : 1.f;
    #pragma unroll
    for (int m=0;m<4;++m){
      int d = dt + tx*4+m;
      long li = (long)srow*D_ + d;
      float v = c3*acc[i][m];
      if (X1) v += c1*X1[x1z*n + li];
      if (X2) v += c2*X2[x2z*n + li];
      out[((long)n*S_ + srow)*D_ + d] = f*v;
    }
  }
}

// ---------------- generic fp32 GEMM (NN), 64x64 tile ----------------
__launch_bounds__(256,1)
__global__ void gemm_nn(const float* __restrict__ A, long az,
                        const float* __restrict__ B, long bz,
                        float* __restrict__ C, long cz,
                        int K, int N,
                        const float* __restrict__ bias, int act)
{
  __shared__ float al[32*68];
  __shared__ float bl[32*68];
  const int mt = blockIdx.x*64, nt = blockIdx.y*64, zz = blockIdx.z;
  const int j = threadIdx.x;
  const float* Ap = A + (long)az*zz;
  const float* Bp = B + (long)bz*zz;
  const int tx = j&15, ty = j>>4;
  float acc[4][4];
  #pragma unroll
  for (int i=0;i<4;++i){acc[i][0]=0;acc[i][1]=0;acc[i][2]=0;acc[i][3]=0;}
  for (int k0=0;k0<K;k0+=32){
    #pragma unroll
    for (int half=0; half<2; ++half){
      int idx = j + half*256;
      int r = idx>>3, kk=(idx&7)*4;
      float4 v = *(const float4*)&Ap[(long)(mt+r)*K + k0+kk];
      al[(kk+0)*68+r]=v.x; al[(kk+1)*68+r]=v.y; al[(kk+2)*68+r]=v.z; al[(kk+3)*68+r]=v.w;
    }
    #pragma unroll
    for (int half=0; half<2; ++half){
      int idx = j + half*256;
      int r = idx>>4, cc=(idx&15)*4;
      *(float4*)&bl[r*68+cc] = *(const float4*)&Bp[(long)(k0+r)*N + nt+cc];
    }
    __syncthreads();
    #pragma unroll
    for (int kk=0;kk<32;++kk){
      float4 a = *(const float4*)&al[kk*68+ty*4];
      float4 b = *(const float4*)&bl[kk*68+tx*4];
      acc[0][0]+=a.x*b.x; acc[0][1]+=a.x*b.y; acc[0][2]+=a.x*b.z; acc[0][3]+=a.x*b.w;
      acc[1][0]+=a.y*b.x; acc[1][1]+=a.y*b.y; acc[1][2]+=a.y*b.z; acc[1][3]+=a.y*b.w;
      acc[2][0]+=a.z*b.x; acc[2][1]+=a.z*b.y; acc[2][2]+=a.z*b.z; acc[2][3]+=a.z*b.w;
      acc[3][0]+=a.w*b.x; acc[3][1]+=a.w*b.y; acc[3][2]+=a.w*b.z; acc[3][3]+=a.w*b.w;
    }
    __syncthreads();
  }
  #pragma unroll
  for (int i=0;i<4;++i){
    int row = mt+ty*4+i;
    #pragma unroll
    for (int m=0;m<4;++m){
      int col = nt+tx*4+m;
      float v = acc[i][m];
      if (bias) v += bias[col];
      if (act==1) v = fmaxf(v,0.f);
      else if (act==2) v = (v>0.f)? v : 0.1f*v;
      C[(long)cz*zz + (long)row*N + col] = v;
    }
  }
}

// ---------------- NT GEMM with scale: C = scale * A @ B^T ----------------
__launch_bounds__(256,1)
__global__ void gemm_nt_scaled(const float* __restrict__ A, const float* __restrict__ B,
                               float* __restrict__ C, int K, float scale)
{
  __shared__ float al[32*68];
  __shared__ float bl[32*68];
  const int mt = blockIdx.x*64, nt = blockIdx.y*64;
  const int j = threadIdx.x;
  const int tx = j&15, ty = j>>4;
  float acc[4][4];
  #pragma unroll
  for (int i=0;i<4;++i){acc[i][0]=0;acc[i][1]=0;acc[i][2]=0;acc[i][3]=0;}
  for (int k0=0;k0<K;k0+=32){
    #pragma unroll
    for (int half=0; half<2; ++half){
      int idx = j + half*256;
      int r = idx>>3, kk=(idx&7)*4;
      float4 v = *(const float4*)&A[(long)(mt+r)*K + k0+kk];
      al[(kk+0)*68+r]=v.x; al[(kk+1)*68+r]=v.y; al[(kk+2)*68+r]=v.z; al[(kk+3)*68+r]=v.w;
    }
    #pragma unroll
    for (int half=0; half<2; ++half){
      int idx = j + half*256;
      int r = idx>>3, kk=(idx&7)*4;
      float4 v = *(const float4*)&B[(long)(nt+r)*K + k0+kk];
      bl[(kk+0)*68+r]=v.x; bl[(kk+1)*68+r]=v.y; bl[(kk+2)*68+r]=v.z; bl[(kk+3)*68+r]=v.w;
    }
    __syncthreads();
    #pragma unroll
    for (int kk=0;kk<32;++kk){
      float4 a = *(const float4*)&al[kk*68+ty*4];
      float4 b = *(const float4*)&bl[kk*68+tx*4];
      acc[0][0]+=a.x*b.x; acc[0][1]+=a.x*b.y; acc[0][2]+=a.x*b.z; acc[0][3]+=a.x*b.w;
      acc[1][0]+=a.y*b.x; acc[1][1]+=a.y*b.y; acc[1][2]+=a.y*b.z; acc[1][3]+=a.y*b.w;
      acc[2][0]+=a.z*b.x; acc[2][1]+=a.z*b.y; acc[2][2]+=a.z*b.z; acc[2][3]+=a.z*b.w;
      acc[3][0]+=a.w*b.x; acc[3][1]+=a.w*b.y; acc[3][2]+=a.w*b.z; acc[3][3]+=a.w*b.w;
    }
    __syncthreads();
  }
  #pragma unroll
  for (int i=0;i<4;++i){
    #pragma unroll
    for (int m=0;m<4;++m){
      C[(long)(mt+ty*4+i)*S_ + nt+tx*4+m] = acc[i][m]*scale;
    }
  }
}

// ---------------- top-k + sparse softmax-gather ----------------
__launch_bounds__(256,1)
__global__ void topk_gather(const float* __restrict__ sim, const float* __restrict__ xs,
                            const int* __restrict__ Kp, float* __restrict__ dynpre)
{
  __shared__ float row[S_];
  __shared__ float work[S_];
  __shared__ float wred[4]; __shared__ int ired[4];
  __shared__ float selw[256]; __shared__ int seli[256];
  __shared__ int cnt; __shared__ float sh_kth, sh_max, sh_den;
  const int s = blockIdx.x, j = threadIdx.x;
  const float* rp = sim + (long)s*S_;
  for (int i=j;i<S_;i+=256){ float v=rp[i]; row[i]=v; work[i]=v; }
  if (j==0) cnt=0;
  __syncthreads();
  const int K = Kp[0];
  for (int it=0; it<K; ++it){
    float m=-3.0e38f; int mi=0;
    for (int i=j;i<S_;i+=256){ float v=work[i]; if (v>m){m=v;mi=i;} }
    #pragma unroll
    for (int o=32;o>=1;o>>=1){
      float om=__shfl_xor(m,o); int oi=__shfl_xor(mi,o);
      if (om>m){m=om;mi=oi;}
    }
    if ((j&63)==0){ wred[j>>6]=m; ired[j>>6]=mi; }
    __syncthreads();
    if (j==0){
      float bm=wred[0]; int bi=ired[0];
      #pragma unroll
      for (int w=1;w<4;++w) if (wred[w]>bm){bm=wred[w];bi=ired[w];}
      work[bi]=-3.0e38f;
      if (it==0) sh_max=bm;
      sh_kth=bm;
    }
    __syncthreads();
  }
  const float kth=sh_kth, rmax=sh_max;
  for (int i=j;i<S_;i+=256){
    float v=row[i];
    if (v>=kth){
      int p=atomicAdd(&cnt,1);
      if (p<256){ seli[p]=i; selw[p]=__expf(v-rmax); }
    }
  }
  __syncthreads();
  int c = cnt; if (c>256) c=256;
  {
    float p = (j<c)? selw[j] : 0.f;
    p = warp_sum64(p);
    if ((j&63)==0) wred[j>>6]=p;
    __syncthreads();
    if (j==0) sh_den = wred[0]+wred[1]+wred[2]+wred[3];
    __syncthreads();
  }
  float acc=0.f;
  for (int l=0;l<c;++l) acc += selw[l]*xs[(long)seli[l]*D_ + j];
  dynpre[(long)s*D_+j] = acc / sh_den;
}

// ---------------- hyper = sum_n ps[n] * reps[n] ----------------
__global__ void hyperwsum_kernel(const float* __restrict__ reps, const float* __restrict__ ps,
                                 float* __restrict__ hyper)
{
  long idx = (long)blockIdx.x*256+threadIdx.x;  // grid 2048
  hyper[idx] = ps[0]*reps[idx] + ps[1]*reps[(long)SD_+idx]
             + ps[2]*reps[2L*SD_+idx] + ps[3]*reps[3L*SD_+idx];
}

// ---------------- fusion ----------------
__global__ void fuse_kernel(const float* __restrict__ xs, const float* __restrict__ dyn,
                            const float* __restrict__ hyper, const float* __restrict__ beta,
                            float* __restrict__ fused)
{
  long idx = (long)blockIdx.x*256+threadIdx.x;  // grid 2048
  float b0=beta[0],b1=beta[1],b2=beta[2];
  float mx=fmaxf(b0,fmaxf(b1,b2));
  float e0=__expf(b0-mx),e1=__expf(b1-mx),e2=__expf(b2-mx);
  float inv=1.f/(e0+e1+e2);
  fused[idx] = e0*inv*xs[idx] + e1*inv*dyn[idx] + e2*inv*hyper[idx];
}

// ---------------- head: out = hh1 @ Wm2 + bm2 ----------------
__global__ void head_kernel(const float* __restrict__ hh1, const float* __restrict__ Wm2,
                            const float* __restrict__ bm2, float* __restrict__ out)
{
  int r = blockIdx.x*32 + (threadIdx.x>>3);   // grid 64
  int sub = threadIdx.x&7;
  const float* hp = hh1 + (long)r*D_;
  float acc=0.f;
  for (int c=sub;c<D_;c+=8) acc += hp[c]*Wm2[c];
  acc += __shfl_xor(acc,1); acc += __shfl_xor(acc,2); acc += __shfl_xor(acc,4);
  if (sub==0) out[r]=acc+bm2[0];
}

// ---------------- launch ----------------
extern "C" void kernel_launch(void* const* d_in, const int* in_sizes, int n_in,
                              void* d_out, int out_size, void* d_ws, size_t ws_size,
                              hipStream_t stream)
{
  (void)in_sizes;(void)n_in;(void)out_size;(void)ws_size;
  const float* x        =(const float*)d_in[0];
  const float* snapshot =(const float*)d_in[1];
  const float* ps       =(const float*)d_in[2];
  const float* beta     =(const float*)d_in[3];
  const float* Wemb=(const float*)d_in[4];  const float* bemb=(const float*)d_in[5];
  const float* Wq  =(const float*)d_in[6];  const float* bq  =(const float*)d_in[7];
  const float* Wk  =(const float*)d_in[8];  const float* bk  =(const float*)d_in[9];
  const float* Wv  =(const float*)d_in[10]; const float* bv  =(const float*)d_in[11];
  const float* Wo  =(const float*)d_in[12]; const float* bo  =(const float*)d_in[13];
  const float* ln1g=(const float*)d_in[14]; const float* ln1b=(const float*)d_in[15];
  const float* Wint=(const float*)d_in[16]; const float* bint=(const float*)d_in[17];
  const float* Wmix=(const float*)d_in[18]; const float* bmix=(const float*)d_in[19];
  const float* ln2g=(const float*)d_in[20]; const float* ln2b=(const float*)d_in[21];
  const float* Wt  =(const float*)d_in[22]; const float* bt  =(const float*)d_in[23];
  const float* vt  =(const float*)d_in[24];
  const float* Wh1 =(const float*)d_in[25]; const float* bh1 =(const float*)d_in[26];
  const float* filt1=(const float*)d_in[27];
  const float* Wh2 =(const float*)d_in[28]; const float* bh2 =(const float*)d_in[29];
  const float* filt2=(const float*)d_in[30];
  const float* Wa  =(const float*)d_in[31]; const float* Wb  =(const float*)d_in[32];
  const float* Wg  =(const float*)d_in[33]; const float* bg  =(const float*)d_in[34];
  const float* Wm1 =(const float*)d_in[35]; const float* bm1 =(const float*)d_in[36];
  const float* Wm2 =(const float*)d_in[37]; const float* bm2 =(const float*)d_in[38];
  const int* numedges=(const int*)d_in[39];
  float* out=(float*)d_out;

  // ---- workspace layout (floats). Peak ~46.5 MB. ----
  float* w = (float*)d_ws;
  float* Ppart = w;
  float* Hn    = w + 4194304;
  float* HnD   = Hn + 1048576;
  float* P     = HnD + 1048576;
  float* Dv    = P + 131072;
  float* De    = Dv + 8192;
  float* pe    = w;            // overlay (dead before first hg_phase1)
  float* repsb = w;            // overlay (after Ppart consumed)
  float* sim   = w;            // overlay (after repsb consumed)
  float* xs    = w + 6431232;
  float* hyper = xs + SD_;
  float* bufA  = hyper + SD_;          // NS*SD
  float* bufB  = bufA + 4*SD_;         // NS*SD
  float* p1    = bufA;
  float* q1    = bufA + SD_;
  float* dynpre= bufA + 2*SD_;
  float* dyn   = bufA + 3*SD_;
  float* fused = bufB;
  float* hh1   = bufB + SD_;
  short* pkc   = (short*)(w + PKBASE);  // 2MB combined packed weights

  hipMemsetAsync(De, 0, (size_t)NS_*E_*sizeof(float), stream);
  pe_kernel<<<64,256,0,stream>>>(pe);
  pack_qkv<<<256,256,0,stream>>>(Wq, pkc+PK_ATT, 0);
  pack_qkv<<<256,256,0,stream>>>(Wk, pkc+PK_ATT, 1);
  pack_qkv<<<256,256,0,stream>>>(Wv, pkc+PK_ATT, 2);
  pack_post<<<256,256,0,stream>>>(Wo,   pkc+PK_WO);
  pack_post<<<256,256,0,stream>>>(Wint, pkc+PK_WI);
  pack_post<<<256,256,0,stream>>>(Wt,   pkc+PK_WT);
  pack_post<<<512,256,0,stream>>>(Wmix, pkc+PK_WM);

  stageA_kernel<<<S_,512,0,stream>>>(x,pe,Wemb,bemb,bq,bk,bv,bo,
                                     ln1g,ln1b,bint,bmix,ln2g,ln2b,bt,vt,
                                     pkc,xs);
  hg_deg<<<dim3(32,NS_),256,0,stream>>>(snapshot,Dv,De);
  hg_scale<<<4096,256,0,stream>>>(snapshot,Dv,De,Hn,HnD);

  auto applyA=[&](const float* M, long mz,
                  const float* X1, long x1z, float c1,
                  const float* X2, long x2z, float c2, float c3,
                  const float* filt, int uf, float* outb){
    hg_phase1<<<dim3(KC_,2,NS_),256,0,stream>>>(Hn,M,mz,Ppart);
    hg_reduceP<<<dim3(32,NS_),256,0,stream>>>(Ppart,P);
    hg_phase2<<<dim3(32,4,NS_),256,0,stream>>>(HnD,P,X1,x1z,c1,X2,x2z,c2,c3,filt,uf,outb);
  };

  // ---- wavelet hypergraph conv, layer 1 ----
  applyA(xs,0,     xs,0,1.f,    nullptr,0,0.f,  -1.f,  nullptr,0, bufA);  // t1 = L z
  applyA(bufA,SD_, xs,0,1.f,    bufA,SD_,1.5f,  -0.5f, filt1,1,   bufB);  // y0
  applyA(bufB,SD_, bufB,SD_,1.f, nullptr,0,0.f, -1.f,  nullptr,0, bufA);  // t3
  applyA(bufA,SD_, bufB,SD_,1.f, bufA,SD_,-0.5f,-0.5f, nullptr,0, bufA);  // p
  gemm_nn<<<dim3(32,4,NS_),256,0,stream>>>(bufA,SD_, Wh1,0, bufB,SD_, 256,256, bh1, 2);

  // ---- layer 2 ----
  applyA(bufB,SD_, bufB,SD_,1.f, nullptr,0,0.f, -1.f,  nullptr,0, bufA);
  applyA(bufA,SD_, bufB,SD_,1.f, bufA,SD_,1.5f, -0.5f, filt2,1,   bufB);
  applyA(bufB,SD_, bufB,SD_,1.f, nullptr,0,0.f, -1.f,  nullptr,0, bufA);
  applyA(bufA,SD_, bufB,SD_,1.f, bufA,SD_,-0.5f,-0.5f, nullptr,0, bufA);
  gemm_nn<<<dim3(32,4,NS_),256,0,stream>>>(bufA,SD_, Wh2,0, repsb,SD_, 256,256, bh2, 0);
  hyperwsum_kernel<<<2048,256,0,stream>>>(repsb,ps,hyper);

  // ---- dynamic graph ----
  gemm_nn<<<dim3(32,4,1),256,0,stream>>>(xs,0, Wa,0, p1,0, 256,256, nullptr, 0);
  gemm_nn<<<dim3(32,4,1),256,0,stream>>>(xs,0, Wb,0, q1,0, 256,256, nullptr, 0);
  gemm_nt_scaled<<<dim3(32,32),256,0,stream>>>(p1,q1,sim,256,0.0625f);
  topk_gather<<<S_,256,0,stream>>>(sim,xs,numedges,dynpre);
  gemm_nn<<<dim3(32,4,1),256,0,stream>>>(dynpre,0, Wg,0, dyn,0, 256,256, bg, 1);

  // ---- fusion + head ----
  fuse_kernel<<<2048,256,0,stream>>>(xs,dyn,hyper,beta,fused);
  gemm_nn<<<dim3(32,4,1),256,0,stream>>>(fused,0, Wm1,0, hh1,0, 256,256, bm1, 1);
  head_kernel<<<64,256,0,stream>>>(hh1,Wm2,bm2,out);
}